// Round 3
// baseline (374.978 us; speedup 1.0000x reference)
//
#include <hip/hip_runtime.h>

#define DEV __device__ __forceinline__
DEV float relu_(float x) { return fmaxf(x, 0.0f); }

typedef __attribute__((ext_vector_type(4))) float f32x4;
typedef __attribute__((ext_vector_type(8))) __bf16 bf16x8;

DEV unsigned short bfbits(__bf16 b) { union { unsigned short s; __bf16 b; } x; x.b = b; return x.s; }
DEV __bf16 bffrom(unsigned short s) { union { unsigned short s; __bf16 b; } x; x.s = s; return x.b; }

// branchy top-5 insert (R6-measured best for wave-coherent merge streams)
DEV void knn_insert(float (&bd)[5], int (&bi)[5], float d, int j) {
  if (d >= bd[4]) return;
  bd[4] = d; bi[4] = j;
#pragma unroll
  for (int p = 4; p > 0; --p) {
    if (bd[p] < bd[p - 1]) {
      float td = bd[p]; bd[p] = bd[p - 1]; bd[p - 1] = td;
      int ti = bi[p]; bi[p] = bi[p - 1]; bi[p - 1] = ti;
    }
  }
}

// branchless EXACT top-5 insert (used in knn1 tree merge)
DEV void knn_insert_bl(float (&bd)[5], int (&bi)[5], float d, int j) {
#pragma unroll
  for (int p = 0; p < 5; ++p) {
    bool lt = d < bd[p];
    float nd = lt ? d : bd[p];
    float cd = lt ? bd[p] : d;
    int ni = lt ? j : bi[p];
    int ci = lt ? bi[p] : j;
    bd[p] = nd; d = cd;
    bi[p] = ni; j = ci;
  }
}

// sorted top-5 insert via med3: new[i] = med3(old[i-1], old[i], x); new[0]=min.
// 5 VALU ops, no index tracking (index packed in low mantissa bits of x).
DEV void ins5(float (&b)[5], float x) {
  b[4] = __builtin_amdgcn_fmed3f(b[3], b[4], x);
  b[3] = __builtin_amdgcn_fmed3f(b[2], b[3], x);
  b[2] = __builtin_amdgcn_fmed3f(b[1], b[2], x);
  b[1] = __builtin_amdgcn_fmed3f(b[0], b[1], x);
  b[0] = fminf(b[0], x);
}

// ---------------- Kernel FRONT: knn1 (blk<2048) + uv (2048..3071) + preps (3072..3179) ----------------
__global__ __launch_bounds__(256) void k_front(
    const float* __restrict__ pos, const float* __restrict__ w1a,
    const float* __restrict__ b1a, const float* __restrict__ w1b,
    const float* __restrict__ w1c, const float* __restrict__ w2,
    const float* __restrict__ wl,
    int* __restrict__ idx1, float* __restrict__ uR, float* __restrict__ vR,
    __bf16* __restrict__ wfh, __bf16* __restrict__ wfl,
    __bf16* __restrict__ wph, __bf16* __restrict__ wpl,
    __bf16* __restrict__ wlb) {
  __shared__ __align__(16) float smem[9472];
  int tid = threadIdx.x;
  int blk = blockIdx.x;
  if (blk < 2048) {
    float* ps = smem;
    float* sqs = smem + 6144;
    float* md = smem + 8192;
    int* mi = (int*)(smem + 8832);
    int b = blk >> 6, qc = blk & 63;
    const float* src = pos + b * 6144;
    for (int u = tid; u < 6144; u += 256) ps[u] = src[u];
    __syncthreads();
    for (int u = tid; u < 2048; u += 256) {
      float x = ps[u * 3], y = ps[u * 3 + 1], z = ps[u * 3 + 2];
      sqs[u] = fmaf(z, z, fmaf(y, y, x * x));
    }
    __syncthreads();
    int q = tid & 31, sub = tid >> 5;
    int qi = qc * 32 + q;
    float qx = ps[qi * 3], qy = ps[qi * 3 + 1], qz = ps[qi * 3 + 2];
    float qsq = sqs[qi];
    // packed scan: idx (8 bits, j-j0) lives in low mantissa bits of d
    float bp[5] = {1e30f, 1e30f, 1e30f, 1e30f, 1e30f};
    int j0 = sub * 256;
    for (int j = j0; j < j0 + 256; ++j) {
      float px = ps[j * 3], py = ps[j * 3 + 1], pz = ps[j * 3 + 2];
      float dot = fmaf(qz, pz, fmaf(qy, py, qx * px));
      float d = fmaxf((qsq + sqs[j]) - 2.0f * dot, 0.0f);
      unsigned u = (__float_as_uint(d) & 0xFFFFFF00u) | (unsigned)(j & 255);
      ins5(bp, __uint_as_float(u));
    }
    float bd[5]; int bi[5];
#pragma unroll
    for (int k = 0; k < 5; ++k) {
      unsigned u = __float_as_uint(bp[k]);
      bd[k] = __uint_as_float(u & 0xFFFFFF00u);
      bi[k] = j0 + (int)(u & 255u);
    }
    for (int half = 4; half >= 1; half >>= 1) {
      __syncthreads();
      if (sub >= half && sub < 2 * half) {
        int slot = (q * 4 + (sub - half)) * 5;
#pragma unroll
        for (int k = 0; k < 5; ++k) { md[slot + k] = bd[k]; mi[slot + k] = bi[k]; }
      }
      __syncthreads();
      if (sub < half) {
        int slot = (q * 4 + sub) * 5;
#pragma unroll
        for (int k = 0; k < 5; ++k) knn_insert_bl(bd, bi, md[slot + k], mi[slot + k]);
      }
    }
    if (sub == 0) {
      int* op = idx1 + (b * 2048 + qi) * 5;
#pragma unroll
      for (int k = 0; k < 5; ++k) op[k] = bi[k];
    }
  } else if (blk < 3072) {
    float* wAs = smem;
    float* bs = smem + 384;
    float* uS = smem + 448;
    float* vS = smem + 4800;
    for (int u = tid; u < 384; u += 256) wAs[u] = w1a[u];
    if (tid < 64) bs[tid] = b1a[tid];
    __syncthreads();
    int lane = tid & 63, fq = tid >> 6;
    int p0 = (blk - 2048) * 64;
    int p = p0 + lane;
    float x0 = pos[p * 3], x1 = pos[p * 3 + 1], x2 = pos[p * 3 + 2];
#pragma unroll
    for (int m = 0; m < 16; ++m) {
      int f = fq * 16 + m;
      float wt0 = wAs[f], wt1 = wAs[64 + f], wt2 = wAs[128 + f];
      float wb0 = wAs[192 + f], wb1 = wAs[256 + f], wb2 = wAs[320 + f];
      float uval = bs[f];
      uval = fmaf(x0, wt0 - wb0, uval);
      uval = fmaf(x1, wt1 - wb1, uval);
      uval = fmaf(x2, wt2 - wb2, uval);
      uS[lane * 68 + f] = uval;
      vS[lane * 68 + f] = fmaf(x2, wb2, fmaf(x1, wb1, x0 * wb0));
    }
    __syncthreads();
#pragma unroll
    for (int it = 0; it < 4; ++it) {
      int g = it * 1024 + tid * 4;
      int pl = g >> 6, f = g & 63;
      float4 uu = *(const float4*)(uS + pl * 68 + f);
      float4 vv = *(const float4*)(vS + pl * 68 + f);
      *(float4*)(uR + (size_t)p0 * 64 + g) = uu;
      *(float4*)(vR + (size_t)p0 * 64 + g) = vv;
    }
  } else {
    int pblk = blk - 3072;
    if (pblk < 4) {
      int t = pblk * 256 + tid;
      int m = t >> 9;
      int rem = t & 511;
      int nb = rem >> 7;
      int rem2 = rem & 127;
      int s = rem2 >> 6, lane = rem2 & 63;
      int k0 = s * 32 + (lane >> 4) * 8;
      int c = nb * 16 + (lane & 15);
      const float* W = m ? w1c : w1b;
      __bf16 oh[8], ol[8];
#pragma unroll
      for (int j = 0; j < 8; ++j) {
        float val = W[(k0 + j) * 64 + c];
        __bf16 h = (__bf16)val;
        oh[j] = h;
        ol[j] = (__bf16)(val - (float)h);
      }
      size_t off = (size_t)m * 4096 + ((size_t)((nb * 2 + s) * 64 + lane)) * 8;
      *(uint4*)(wfh + off) = *(const uint4*)oh;
      *(uint4*)(wfl + off) = *(const uint4*)ol;
    } else if (pblk < 12) {
      int t = (pblk - 4) * 256 + tid;
      int nb = t >> 7;
      int rem = t & 127;
      int ks = rem >> 6, lane = rem & 63;
      int k0 = ks * 32 + (lane >> 4) * 8;
      int col16 = lane & 15;
      __bf16 oh[8], ol[8];
#pragma unroll
      for (int j = 0; j < 8; ++j) {
        int k = k0 + j;
        float val;
        if (nb < 8) {
          int c = nb * 16 + col16;
          val = w2[k * 128 + c] - w2[(64 + k) * 128 + c];
        } else {
          int c = (nb - 8) * 16 + col16;
          val = w2[(64 + k) * 128 + c];
        }
        __bf16 h = (__bf16)val;
        oh[j] = h;
        ol[j] = (__bf16)(val - (float)h);
      }
      *(uint4*)(wph + (size_t)t * 8) = *(const uint4*)oh;
      *(uint4*)(wpl + (size_t)t * 8) = *(const uint4*)ol;
    } else {
      int t = (pblk - 12) * 256 + tid;
      int nt = t / 3072;
      int rem = t - nt * 3072;
      int ks = rem / 512;
      int rem2 = rem - ks * 512;
      int nb = rem2 >> 6, lane = rem2 & 63;
      int k0 = ks * 32 + (lane >> 4) * 8;
      int n = nt * 128 + nb * 16 + (lane & 15);
      __bf16 o[8];
#pragma unroll
      for (int j = 0; j < 8; ++j) o[j] = (__bf16)wl[(k0 + j) * 1024 + n];
      *(uint4*)(wlb + (size_t)t * 8) = *(const uint4*)o;
    }
  }
}

// ---------------- Kernel 2: EdgeConv1 layers 2/3 via hi/lo MFMA, barrier-free k-loop ----------------
__global__ __launch_bounds__(256) void k_edge1(
    const int* __restrict__ idx1, const float* __restrict__ uR,
    const float* __restrict__ vR,
    const float* __restrict__ s1a, const float* __restrict__ h1a,
    const float* __restrict__ b1b, const float* __restrict__ s1b,
    const float* __restrict__ h1b,
    const float* __restrict__ b1c, const float* __restrict__ s1c,
    const float* __restrict__ h1c,
    const __bf16* __restrict__ wfh, const __bf16* __restrict__ wfl,
    __bf16* __restrict__ xh, __bf16* __restrict__ xl,
    float* __restrict__ sqo, __bf16* __restrict__ xb) {
  __shared__ __align__(16) __bf16 Wh[8192], Wl[8192];
  __shared__ __align__(16) unsigned h2b[4 * 1088];
  int tid = threadIdx.x;
  int w = tid >> 6, lane = tid & 63;
  int quad = lane >> 4, lm = lane & 15;
#pragma unroll
  for (int it = 0; it < 4; ++it) {
    int u4 = it * 256 + tid;
    *(uint4*)(Wh + (size_t)u4 * 8) = *(const uint4*)(wfh + (size_t)u4 * 8);
    *(uint4*)(Wl + (size_t)u4 * 8) = *(const uint4*)(wfl + (size_t)u4 * 8);
  }
  int p0 = blockIdx.x * 64;
  int b = p0 >> 11;
  size_t bb = (size_t)b * 2048;
  int edge = p0 + w * 16 + lm;
  float sA[2][8], hA[2][8];
#pragma unroll
  for (int s = 0; s < 2; ++s)
#pragma unroll
    for (int j = 0; j < 8; ++j) {
      int k = s * 32 + quad * 8 + j;
      sA[s][j] = s1a[k]; hA[s][j] = h1a[k];
    }
  float bB[4], sB[4], hB[4], bC[4], sC[4], hC[4];
#pragma unroll
  for (int nb = 0; nb < 4; ++nb) {
    int c = nb * 16 + lm;
    bB[nb] = b1b[c]; sB[nb] = s1b[c]; hB[nb] = h1b[c];
    bC[nb] = b1c[c]; sC[nb] = s1c[c]; hC[nb] = h1c[c];
  }
  unsigned* h2w = h2b + w * 1088;
  f32x4 mmax[4];
#pragma unroll
  for (int nb = 0; nb < 4; ++nb)
    mmax[nb] = (f32x4){-3.4e38f, -3.4e38f, -3.4e38f, -3.4e38f};
  __syncthreads();
  const float* urow = uR + (size_t)edge * 64;
  for (int kk = 0; kk < 5; ++kk) {
    int jn = idx1[edge * 5 + kk];
    const float* vrow = vR + (bb + jn) * 64;
    bf16x8 Ah[2], Al[2];
#pragma unroll
    for (int s = 0; s < 2; ++s) {
      int off = s * 32 + quad * 8;
      float4 u0 = *(const float4*)(urow + off);
      float4 u1 = *(const float4*)(urow + off + 4);
      float4 v0 = *(const float4*)(vrow + off);
      float4 v1 = *(const float4*)(vrow + off + 4);
      float uv[8] = {u0.x + v0.x, u0.y + v0.y, u0.z + v0.z, u0.w + v0.w,
                     u1.x + v1.x, u1.y + v1.y, u1.z + v1.z, u1.w + v1.w};
      __bf16 th[8], tl[8];
#pragma unroll
      for (int j = 0; j < 8; ++j) {
        float val = relu_(uv[j]) * sA[s][j] + hA[s][j];
        __bf16 hb = (__bf16)val;
        th[j] = hb;
        tl[j] = (__bf16)(val - (float)hb);
      }
      Ah[s] = *(const bf16x8*)th;
      Al[s] = *(const bf16x8*)tl;
    }
#pragma unroll
    for (int nb = 0; nb < 4; ++nb) {
      bf16x8 Bh0 = *(const bf16x8*)(Wh + ((size_t)((nb * 2 + 0) * 64 + lane)) * 8);
      bf16x8 Bh1 = *(const bf16x8*)(Wh + ((size_t)((nb * 2 + 1) * 64 + lane)) * 8);
      bf16x8 Bl0 = *(const bf16x8*)(Wl + ((size_t)((nb * 2 + 0) * 64 + lane)) * 8);
      bf16x8 Bl1 = *(const bf16x8*)(Wl + ((size_t)((nb * 2 + 1) * 64 + lane)) * 8);
      f32x4 a2 = {0.f, 0.f, 0.f, 0.f};
      a2 = __builtin_amdgcn_mfma_f32_16x16x32_bf16(Ah[0], Bh0, a2, 0, 0, 0);
      a2 = __builtin_amdgcn_mfma_f32_16x16x32_bf16(Ah[1], Bh1, a2, 0, 0, 0);
      a2 = __builtin_amdgcn_mfma_f32_16x16x32_bf16(Ah[0], Bl0, a2, 0, 0, 0);
      a2 = __builtin_amdgcn_mfma_f32_16x16x32_bf16(Ah[1], Bl1, a2, 0, 0, 0);
      a2 = __builtin_amdgcn_mfma_f32_16x16x32_bf16(Al[0], Bh0, a2, 0, 0, 0);
      a2 = __builtin_amdgcn_mfma_f32_16x16x32_bf16(Al[1], Bh1, a2, 0, 0, 0);
#pragma unroll
      for (int r = 0; r < 4; ++r) {
        float vv2 = relu_(a2[r] + bB[nb]) * sB[nb] + hB[nb];
        __bf16 hb = (__bf16)vv2;
        __bf16 lb = (__bf16)(vv2 - (float)hb);
        h2w[(quad * 4 + r) * 68 + nb * 16 + lm] =
            (unsigned)bfbits(hb) | ((unsigned)bfbits(lb) << 16);
      }
    }
    bf16x8 A3h[2], A3l[2];
#pragma unroll
    for (int s = 0; s < 2; ++s) {
      const unsigned* rp = h2w + lm * 68 + s * 32 + quad * 8;
      uint4 da = *(const uint4*)rp;
      uint4 db = *(const uint4*)(rp + 4);
      unsigned dw[8] = {da.x, da.y, da.z, da.w, db.x, db.y, db.z, db.w};
      __bf16 th[8], tl[8];
#pragma unroll
      for (int j = 0; j < 8; ++j) {
        th[j] = bffrom((unsigned short)(dw[j] & 0xFFFFu));
        tl[j] = bffrom((unsigned short)(dw[j] >> 16));
      }
      A3h[s] = *(const bf16x8*)th;
      A3l[s] = *(const bf16x8*)tl;
    }
#pragma unroll
    for (int nb = 0; nb < 4; ++nb) {
      bf16x8 Bh0 = *(const bf16x8*)(Wh + 4096 + ((size_t)((nb * 2 + 0) * 64 + lane)) * 8);
      bf16x8 Bh1 = *(const bf16x8*)(Wh + 4096 + ((size_t)((nb * 2 + 1) * 64 + lane)) * 8);
      bf16x8 Bl0 = *(const bf16x8*)(Wl + 4096 + ((size_t)((nb * 2 + 0) * 64 + lane)) * 8);
      bf16x8 Bl1 = *(const bf16x8*)(Wl + 4096 + ((size_t)((nb * 2 + 1) * 64 + lane)) * 8);
      f32x4 a3 = {0.f, 0.f, 0.f, 0.f};
      a3 = __builtin_amdgcn_mfma_f32_16x16x32_bf16(A3h[0], Bh0, a3, 0, 0, 0);
      a3 = __builtin_amdgcn_mfma_f32_16x16x32_bf16(A3h[1], Bh1, a3, 0, 0, 0);
      a3 = __builtin_amdgcn_mfma_f32_16x16x32_bf16(A3h[0], Bl0, a3, 0, 0, 0);
      a3 = __builtin_amdgcn_mfma_f32_16x16x32_bf16(A3h[1], Bl1, a3, 0, 0, 0);
      a3 = __builtin_amdgcn_mfma_f32_16x16x32_bf16(A3l[0], Bh0, a3, 0, 0, 0);
      a3 = __builtin_amdgcn_mfma_f32_16x16x32_bf16(A3l[1], Bh1, a3, 0, 0, 0);
#pragma unroll
      for (int r = 0; r < 4; ++r) mmax[nb][r] = fmaxf(mmax[nb][r], a3[r]);
    }
  }
  float sqp[4] = {0.f, 0.f, 0.f, 0.f};
#pragma unroll
  for (int nb = 0; nb < 4; ++nb) {
    int c = nb * 16 + lm;
#pragma unroll
    for (int r = 0; r < 4; ++r) {
      float vv3 = relu_(mmax[nb][r] + bC[nb]) * sC[nb] + hC[nb];
      sqp[r] = fmaf(vv3, vv3, sqp[r]);
      __bf16 hb = (__bf16)vv3;
      __bf16 lb = (__bf16)(vv3 - (float)hb);
      int n = p0 + w * 16 + quad * 4 + r;
      xh[(size_t)n * 64 + c] = hb;
      xl[(size_t)n * 64 + c] = lb;
      xb[(size_t)n * 192 + c] = hb;
    }
  }
#pragma unroll
  for (int r = 0; r < 4; ++r) {
    float s = sqp[r];
    s += __shfl_xor(s, 1);
    s += __shfl_xor(s, 2);
    s += __shfl_xor(s, 4);
    s += __shfl_xor(s, 8);
    if (lm == 0) sqo[p0 + w * 16 + quad * 4 + r] = s;
  }
}

// ---------------- Kernel MID: knn2 (blk<1024) + pq_mfma (1024..2047) ----------------
// 512 threads = 2 groups x 4 waves; groups split candidates (knn2) / weight chunks (pq).
// LDS 45KB -> 3 blocks/CU = 24 waves/CU (fixes the 43% occupancy tail of R2).
__global__ __launch_bounds__(512) void k_mid(const __bf16* __restrict__ xh,
                                             const __bf16* __restrict__ xl,
                                             const float* __restrict__ sq,
                                             int* __restrict__ idx2,
                                             const __bf16* __restrict__ wph,
                                             const __bf16* __restrict__ wpl,
                                             __bf16* __restrict__ Pb,
                                             __bf16* __restrict__ Qb) {
  __shared__ __align__(16) float smem[11264];
  int tid = threadIdx.x;
  int g = tid >> 8;          // group 0/1
  int t = tid & 255;         // within-group thread
  int ww = t >> 6;           // within-group wave 0..3
  int lane = tid & 63;
  int quad = lane >> 4, lm = lane & 15;
  if (blockIdx.x < 1024) {
    __bf16* Bh = (__bf16*)(smem + g * 4608);
    __bf16* Bl = (__bf16*)(smem + g * 4608 + 2304);
    float* sqs = smem + 9216;
    int b = blockIdx.x >> 5, qc = blockIdx.x & 31;
    int q0 = qc * 64;
    size_t bb = (size_t)b * 2048;
    *(float4*)(sqs + tid * 4) = *(const float4*)(sq + bb + tid * 4);
    const __bf16* qh = xh + (bb + q0 + ww * 16 + lm) * 64 + quad * 8;
    const __bf16* ql = xl + (bb + q0 + ww * 16 + lm) * 64 + quad * 8;
    bf16x8 Ah0 = *(const bf16x8*)(qh);
    bf16x8 Ah1 = *(const bf16x8*)(qh + 32);
    bf16x8 Al0 = *(const bf16x8*)(ql);
    bf16x8 Al1 = *(const bf16x8*)(ql + 32);
    __syncthreads();
    float qsq[4];
#pragma unroll
    for (int r = 0; r < 4; ++r) qsq[r] = sqs[q0 + ww * 16 + quad * 4 + r];
    // packed scan: key6 = it*4+nt (6 bits) in low mantissa bits; lm + group implicit
    float bp[4][5];
#pragma unroll
    for (int r = 0; r < 4; ++r)
#pragma unroll
      for (int k = 0; k < 5; ++k) bp[r][k] = 1e30f;
    for (int it = 0; it < 16; ++it) {
      int ct = g * 16 + it;  // each group stages+scans its own candidate half
#pragma unroll
      for (int pass = 0; pass < 2; ++pass) {
        int unit = pass * 256 + t;
        int n = unit >> 3, cc = unit & 7;
        const __bf16* gsrc = xh + (bb + ct * 64 + n) * 64 + cc * 8;
        const __bf16* gsrl = xl + (bb + ct * 64 + n) * 64 + cc * 8;
        *(uint4*)(Bh + n * 72 + cc * 8) = *(const uint4*)gsrc;
        *(uint4*)(Bl + n * 72 + cc * 8) = *(const uint4*)gsrl;
      }
      __syncthreads();
#pragma unroll
      for (int nt = 0; nt < 4; ++nt) {
        const __bf16* bph = Bh + (nt * 16 + lm) * 72 + quad * 8;
        const __bf16* bpl = Bl + (nt * 16 + lm) * 72 + quad * 8;
        bf16x8 Bh0 = *(const bf16x8*)(bph);
        bf16x8 Bh1 = *(const bf16x8*)(bph + 32);
        bf16x8 Bl0 = *(const bf16x8*)(bpl);
        bf16x8 Bl1 = *(const bf16x8*)(bpl + 32);
        f32x4 acc = {0.f, 0.f, 0.f, 0.f};
        acc = __builtin_amdgcn_mfma_f32_16x16x32_bf16(Ah0, Bh0, acc, 0, 0, 0);
        acc = __builtin_amdgcn_mfma_f32_16x16x32_bf16(Ah1, Bh1, acc, 0, 0, 0);
        acc = __builtin_amdgcn_mfma_f32_16x16x32_bf16(Ah0, Bl0, acc, 0, 0, 0);
        acc = __builtin_amdgcn_mfma_f32_16x16x32_bf16(Ah1, Bl1, acc, 0, 0, 0);
        acc = __builtin_amdgcn_mfma_f32_16x16x32_bf16(Al0, Bh0, acc, 0, 0, 0);
        acc = __builtin_amdgcn_mfma_f32_16x16x32_bf16(Al1, Bh1, acc, 0, 0, 0);
        float csq = sqs[ct * 64 + nt * 16 + lm];
        unsigned key = (unsigned)(it * 4 + nt);
#pragma unroll
        for (int r = 0; r < 4; ++r) {
          float d = fmaxf((qsq[r] + csq) - 2.0f * acc[r], 0.0f);
          unsigned u = (__float_as_uint(d) & 0xFFFFFFC0u) | key;
          ins5(bp[r], __uint_as_float(u));
        }
      }
      __syncthreads();
    }
    float bd[4][5];
    int bi[4][5];
#pragma unroll
    for (int r = 0; r < 4; ++r)
#pragma unroll
      for (int k = 0; k < 5; ++k) {
        unsigned u = __float_as_uint(bp[r][k]);
        bd[r][k] = __uint_as_float(u & 0xFFFFFFC0u);
        bi[r][k] = (((int)(u & 63u)) << 4) + lm + (g << 10);
      }
    // exact wave merge across the 16 lm lanes of each quad
    for (int m = 1; m <= 8; m <<= 1) {
#pragma unroll
      for (int r = 0; r < 4; ++r) {
        float od[5]; int oi[5];
#pragma unroll
        for (int k = 0; k < 5; ++k) {
          od[k] = __shfl_xor(bd[r][k], m);
          oi[k] = __shfl_xor(bi[r][k], m);
        }
#pragma unroll
        for (int k = 0; k < 5; ++k) knn_insert(bd[r], bi[r], od[k], oi[k]);
      }
    }
    // cross-group merge via LDS (group0 cid < group1 cid -> strict < keeps lower-index ties)
    float* md = smem;
    int* mi = (int*)(smem + 320);
    if (g == 1 && lm == 0) {
#pragma unroll
      for (int r = 0; r < 4; ++r) {
        int row = ww * 16 + quad * 4 + r;
#pragma unroll
        for (int k = 0; k < 5; ++k) { md[row * 5 + k] = bd[r][k]; mi[row * 5 + k] = bi[r][k]; }
      }
    }
    __syncthreads();
    if (g == 0) {
#pragma unroll
      for (int r = 0; r < 4; ++r) {
        int row = ww * 16 + quad * 4 + r;
#pragma unroll
        for (int k = 0; k < 5; ++k) knn_insert(bd[r], bi[r], md[row * 5 + k], mi[row * 5 + k]);
      }
      if (lm == 0) {
#pragma unroll
        for (int r = 0; r < 4; ++r) {
          int qi = q0 + ww * 16 + quad * 4 + r;
          int* op = idx2 + (bb + qi) * 5;
#pragma unroll
          for (int k = 0; k < 5; ++k) op[k] = bi[r][k];
        }
      }
    }
  } else {
    __bf16* Wh = (__bf16*)(smem + g * 4096);
    __bf16* Wl = (__bf16*)(smem + g * 4096 + 2048);
    int n0 = (blockIdx.x - 1024) * 64;
    const __bf16* ah = xh + (size_t)(n0 + ww * 16 + lm) * 64 + quad * 8;
    const __bf16* al = xl + (size_t)(n0 + ww * 16 + lm) * 64 + quad * 8;
    bf16x8 Ah0 = *(const bf16x8*)(ah);
    bf16x8 Ah1 = *(const bf16x8*)(ah + 32);
    bf16x8 Al0 = *(const bf16x8*)(al);
    bf16x8 Al1 = *(const bf16x8*)(al + 32);
    for (int c2 = 0; c2 < 2; ++c2) {
      int chunk = g * 2 + c2;  // group g handles chunks {2g, 2g+1}
      __syncthreads();
#pragma unroll
      for (int it = 0; it < 2; ++it) {
        int unit = it * 256 + t;
        *(uint4*)(Wh + (size_t)unit * 8) =
            *(const uint4*)(wph + (size_t)chunk * 4096 + (size_t)unit * 8);
        *(uint4*)(Wl + (size_t)unit * 8) =
            *(const uint4*)(wpl + (size_t)chunk * 4096 + (size_t)unit * 8);
      }
      __syncthreads();
#pragma unroll
      for (int nb4 = 0; nb4 < 4; ++nb4) {
        int nb = chunk * 4 + nb4;
        bf16x8 Bh0 = *(const bf16x8*)(Wh + ((size_t)(nb4 * 2 + 0) * 64 + lane) * 8);
        bf16x8 Bh1 = *(const bf16x8*)(Wh + ((size_t)(nb4 * 2 + 1) * 64 + lane) * 8);
        bf16x8 Bl0 = *(const bf16x8*)(Wl + ((size_t)(nb4 * 2 + 0) * 64 + lane) * 8);
        bf16x8 Bl1 = *(const bf16x8*)(Wl + ((size_t)(nb4 * 2 + 1) * 64 + lane) * 8);
        f32x4 acc = {0.f, 0.f, 0.f, 0.f};
        acc = __builtin_amdgcn_mfma_f32_16x16x32_bf16(Ah0, Bh0, acc, 0, 0, 0);
        acc = __builtin_amdgcn_mfma_f32_16x16x32_bf16(Ah1, Bh1, acc, 0, 0, 0);
        acc = __builtin_amdgcn_mfma_f32_16x16x32_bf16(Ah0, Bl0, acc, 0, 0, 0);
        acc = __builtin_amdgcn_mfma_f32_16x16x32_bf16(Ah1, Bl1, acc, 0, 0, 0);
        acc = __builtin_amdgcn_mfma_f32_16x16x32_bf16(Al0, Bh0, acc, 0, 0, 0);
        acc = __builtin_amdgcn_mfma_f32_16x16x32_bf16(Al1, Bh1, acc, 0, 0, 0);
        bool isP = (nb < 8);
        __bf16* base = isP ? Pb : Qb;
        int col = (isP ? nb : nb - 8) * 16 + lm;
#pragma unroll
        for (int r = 0; r < 4; ++r) {
          int n = n0 + ww * 16 + quad * 4 + r;
          base[(size_t)n * 128 + col] = (__bf16)acc[r];
        }
      }
    }
  }
}

// ---------------- Kernel 4b: gather-max + activation, 4 channels/lane ----------------
// grid 8192 (8 points/block); per-channel math order identical (bit-exact)
__global__ __launch_bounds__(256) void k_gmax(const __bf16* __restrict__ Pb,
                                              const __bf16* __restrict__ Qb,
                                              const int* __restrict__ idx2,
                                              const float* __restrict__ b2,
                                              const float* __restrict__ s2,
                                              const float* __restrict__ h2v,
                                              __bf16* __restrict__ xb) {
  int tid = threadIdx.x;
  int c4 = tid & 31, p = tid >> 5;  // 32 lanes/point, 8 points/block
  int n = blockIdx.x * 8 + p;
  int b = n >> 11;
  const int* ip = idx2 + n * 5;
  int c0 = c4 * 4;
  float m[4] = {-3.4e38f, -3.4e38f, -3.4e38f, -3.4e38f};
#pragma unroll
  for (int k = 0; k < 5; ++k) {
    int j = ip[k];
    uint2 q = *(const uint2*)(Qb + ((size_t)(b * 2048 + j)) * 128 + c0);
    m[0] = fmaxf(m[0], (float)bffrom((unsigned short)(q.x & 0xFFFFu)));
    m[1] = fmaxf(m[1], (float)bffrom((unsigned short)(q.x >> 16)));
    m[2] = fmaxf(m[2], (float)bffrom((unsigned short)(q.y & 0xFFFFu)));
    m[3] = fmaxf(m[3], (float)bffrom((unsigned short)(q.y >> 16)));
  }
  uint2 pv = *(const uint2*)(Pb + (size_t)n * 128 + c0);
  float pvf[4] = {(float)bffrom((unsigned short)(pv.x & 0xFFFFu)),
                  (float)bffrom((unsigned short)(pv.x >> 16)),
                  (float)bffrom((unsigned short)(pv.y & 0xFFFFu)),
                  (float)bffrom((unsigned short)(pv.y >> 16))};
  __bf16 o[4];
#pragma unroll
  for (int i = 0; i < 4; ++i) {
    float v = pvf[i] + m[i] + b2[c0 + i];
    o[i] = (__bf16)(relu_(v) * s2[c0 + i] + h2v[c0 + i]);
  }
  uint2 ov;
  ov.x = (unsigned)bfbits(o[0]) | ((unsigned)bfbits(o[1]) << 16);
  ov.y = (unsigned)bfbits(o[2]) | ((unsigned)bfbits(o[3]) << 16);
  *(uint2*)(xb + (size_t)n * 192 + 64 + c0) = ov;
}

// ---------------- Kernel 5: bf16 MFMA GEMM fused point-max, A staged once, ng loop ----------------
// grid 1024 (mg); LDS: Aall 24KB + B chunk 16KB = 40KB -> 4 blocks/CU (= grid/256CU)
__global__ __launch_bounds__(256) void k_linl_mfma(const __bf16* __restrict__ xb,
                                                   const __bf16* __restrict__ wlb,
                                                   float* __restrict__ pool_part) {
  __shared__ __align__(16) __bf16 Aall[12288];  // [mb4][ks6][lane64][8]
  __shared__ __align__(16) __bf16 Bl[8192];     // [nt2][nb8][lane64][8]
  int tid = threadIdx.x;
  int w = tid >> 6, lane = tid & 63;
  int mg = blockIdx.x;
  int n0 = mg << 6;
  int quad = lane >> 4, lm = lane & 15;
  // stage ALL of this mg's A-tile once (1536 uint4)
#pragma unroll
  for (int it = 0; it < 6; ++it) {
    int unit = it * 256 + tid;           // 0..1535
    int mb = unit / 384;
    int rem = unit - mb * 384;
    int ks = rem >> 6, ln = rem & 63;
    int lmm = ln & 15, qd = ln >> 4;
    const uint4* ga = (const uint4*)(xb + (size_t)(n0 + mb * 16 + lmm) * 192 + ks * 32 + qd * 8);
    *(uint4*)(Aall + ((size_t)(mb * 6 + ks) * 64 + ln) * 8) = *ga;
  }
  for (int ng = 0; ng < 4; ++ng) {
    f32x4 acc[4][4];
#pragma unroll
    for (int i = 0; i < 4; ++i)
#pragma unroll
      for (int j = 0; j < 4; ++j) acc[i][j] = (f32x4){0.f, 0.f, 0.f, 0.f};
    for (int ks = 0; ks < 6; ++ks) {
      __syncthreads();  // protect prev B reads (and covers initial A staging)
#pragma unroll
      for (int nt2 = 0; nt2 < 2; ++nt2) {
#pragma unroll
        for (int u = 0; u < 2; ++u) {
          int unit = u * 256 + tid;
          const uint4* gb = (const uint4*)(wlb + ((size_t)((ng * 2 + nt2) * 6 + ks)) * 4096 + (size_t)unit * 8);
          *(uint4*)(Bl + (size_t)nt2 * 4096 + (size_t)unit * 8) = *gb;
        }
      }
      __syncthreads();
      bf16x8 af[4], bfr[4];
#pragma unroll
      for (int i = 0; i < 4; ++i)
        af[i] = *(const bf16x8*)(Aall + ((size_t)(i * 6 + ks) * 64 + lane) * 8);
      int nt2 = w >> 1, nbb = (w & 1) * 4;
#pragma unroll
      for (int j = 0; j < 4; ++j)
        bfr[j] = *(const bf16x8*)(Bl + (size_t)nt2 * 4096 + ((size_t)((nbb + j) * 64 + lane)) * 8);
#pragma unroll
      for (int i = 0; i < 4; ++i)
#pragma unroll
        for (int j = 0; j < 4; ++j)
          acc[i][j] = __builtin_amdgcn_mfma_f32_16x16x32_bf16(af[i], bfr[j], acc[i][j], 0, 0, 0);
    }
#pragma unroll
    for (int j = 0; j < 4; ++j) {
      float m = -3.4e38f;
#pragma unroll
      for (int i = 0; i < 4; ++i)
#pragma unroll
        for (int r = 0; r < 4; ++r) m = fmaxf(m, acc[i][j][r]);
      m = fmaxf(m, __shfl_xor(m, 16));
      m = fmaxf(m, __shfl_xor(m, 32));
      if (quad == 0) {
        int ch = ng * 256 + (w >> 1) * 128 + (w & 1) * 64 + j * 16 + lm;
        pool_part[(size_t)mg * 1024 + ch] = m;
      }
    }
  }
}

// ---------------- Kernel 6a: pool merge (32-way max) + lin/bn -> p[32][1024]; zeroes out ----------------
// grid 128 (32 b x 4 cblk), 256 thr: 1 channel/thread, 32 strided loads w/ 4-way ILP
__global__ __launch_bounds__(256) void k_pool(const float* __restrict__ pool_part,
                                              const float* __restrict__ bl,
                                              const float* __restrict__ sl,
                                              const float* __restrict__ hl,
                                              float* __restrict__ p,
                                              float* __restrict__ out) {
  int b = blockIdx.x >> 2, cb = blockIdx.x & 3;
  int c = cb * 256 + threadIdx.x;
  const float* src = pool_part + (size_t)(b * 32) * 1024 + c;
  float m0 = -3.4e38f, m1 = -3.4e38f, m2 = -3.4e38f, m3 = -3.4e38f;
#pragma unroll
  for (int t = 0; t < 32; t += 4) {
    m0 = fmaxf(m0, src[(size_t)t * 1024]);
    m1 = fmaxf(m1, src[(size_t)(t + 1) * 1024]);
    m2 = fmaxf(m2, src[(size_t)(t + 2) * 1024]);
    m3 = fmaxf(m3, src[(size_t)(t + 3) * 1024]);
  }
  float m = fmaxf(fmaxf(m0, m1), fmaxf(m2, m3));
  p[b * 1024 + c] = relu_(m + bl[c]) * sl[c] + hl[c];
  if (blockIdx.x == 0 && threadIdx.x < 64) out[threadIdx.x] = 0.0f;
}

// ---------------- Kernel 6b: h1 = act(p @ wm1) ----------------
// grid 256 (32 b x 8 cblk), 256 thr: 4 waves split the 1024-deep f-dim, LDS reduce
__global__ __launch_bounds__(256) void k_m1(const float* __restrict__ p,
                                            const float* __restrict__ wm1,
                                            const float* __restrict__ bm1,
                                            const float* __restrict__ sm1,
                                            const float* __restrict__ hm1,
                                            float* __restrict__ h1) {
  __shared__ float p_s[1024];
  __shared__ float red[4][64];
  int b = blockIdx.x >> 3, cb = blockIdx.x & 7;
  int tid = threadIdx.x;
  for (int u = tid; u < 1024; u += 256) p_s[u] = p[b * 1024 + u];
  __syncthreads();
  int c64 = tid & 63, q = tid >> 6;
  int C = cb * 64 + c64;
  int f0 = q * 256;
  const float* W = wm1 + (size_t)f0 * 512 + C;
  float a[8] = {0.f, 0.f, 0.f, 0.f, 0.f, 0.f, 0.f, 0.f};
  for (int f = 0; f < 256; f += 8) {
#pragma unroll
    for (int u = 0; u < 8; ++u)
      a[u] = fmaf(p_s[f0 + f + u], W[(size_t)(f + u) * 512], a[u]);
  }
  red[q][c64] = ((a[0] + a[1]) + (a[2] + a[3])) + ((a[4] + a[5]) + (a[6] + a[7]));
  __syncthreads();
  if (tid < 64) {
    float t = (red[0][tid] + red[1][tid]) + (red[2][tid] + red[3][tid]);
    int C2 = cb * 64 + tid;
    h1[b * 512 + C2] = relu_(t + bm1[C2]) * sm1[C2] + hm1[C2];
  }
}

// ---------------- Kernel 6c: h2 = act(h1 @ wm2); out += h2-slice @ wout (atomic partials) ----------------
// grid 128 (32 b x 4 cblk), 256 thr
__global__ __launch_bounds__(256) void k_m2o(const float* __restrict__ h1,
                                             const float* __restrict__ wm2,
                                             const float* __restrict__ bm2,
                                             const float* __restrict__ sm2,
                                             const float* __restrict__ hm2,
                                             const float* __restrict__ wout,
                                             const float* __restrict__ bout,
                                             float* __restrict__ out) {
  __shared__ float h1_s[512];
  __shared__ float red[4][64];
  int b = blockIdx.x >> 2, cb = blockIdx.x & 3;
  int tid = threadIdx.x;
  for (int u = tid; u < 512; u += 256) h1_s[u] = h1[b * 512 + u];
  __syncthreads();
  int c64 = tid & 63, q = tid >> 6;
  int C = cb * 64 + c64;
  int f0 = q * 128;
  const float* W = wm2 + (size_t)f0 * 256 + C;
  float a[4] = {0.f, 0.f, 0.f, 0.f};
  for (int f = 0; f < 128; f += 4) {
#pragma unroll
    for (int u = 0; u < 4; ++u)
      a[u] = fmaf(h1_s[f0 + f + u], W[(size_t)(f + u) * 256], a[u]);
  }
  red[q][c64] = (a[0] + a[1]) + (a[2] + a[3]);
  __syncthreads();
  if (tid < 64) {
    float t = (red[0][tid] + red[1][tid]) + (red[2][tid] + red[3][tid]);
    int C2 = cb * 64 + tid;
    float h2v = relu_(t + bm2[C2]) * sm2[C2] + hm2[C2];
    float2 wv = *(const float2*)(wout + C2 * 2);
    float v0 = h2v * wv.x, v1 = h2v * wv.y;
#pragma unroll
    for (int m = 1; m < 64; m <<= 1) {
      v0 += __shfl_xor(v0, m);
      v1 += __shfl_xor(v1, m);
    }
    if (tid == 0) {
      if (cb == 0) { v0 += bout[0]; v1 += bout[1]; }
      atomicAdd(&out[b * 2], v0);
      atomicAdd(&out[b * 2 + 1], v1);
    }
  }
}

extern "C" void kernel_launch(void* const* d_in, const int* in_sizes, int n_in,
                              void* d_out, int out_size, void* d_ws, size_t ws_size,
                              hipStream_t stream) {
  const float* pos = (const float*)d_in[0];
  const float* w1a = (const float*)d_in[1];
  const float* b1a = (const float*)d_in[2];
  const float* s1a = (const float*)d_in[3];
  const float* h1a = (const float*)d_in[4];
  const float* w1b = (const float*)d_in[5];
  const float* b1b = (const float*)d_in[6];
  const float* s1b = (const float*)d_in[7];
  const float* h1b = (const float*)d_in[8];
  const float* w1c = (const float*)d_in[9];
  const float* b1c = (const float*)d_in[10];
  const float* s1c = (const float*)d_in[11];
  const float* h1c = (const float*)d_in[12];
  const float* w2 = (const float*)d_in[13];
  const float* b2 = (const float*)d_in[14];
  const float* s2 = (const float*)d_in[15];
  const float* h2 = (const float*)d_in[16];
  const float* wl = (const float*)d_in[17];
  const float* bl = (const float*)d_in[18];
  const float* sl = (const float*)d_in[19];
  const float* hl = (const float*)d_in[20];
  const float* wm1 = (const float*)d_in[21];
  const float* bm1 = (const float*)d_in[22];
  const float* sm1 = (const float*)d_in[23];
  const float* hm1 = (const float*)d_in[24];
  const float* wm2 = (const float*)d_in[25];
  const float* bm2 = (const float*)d_in[26];
  const float* sm2 = (const float*)d_in[27];
  const float* hm2 = (const float*)d_in[28];
  const float* wout = (const float*)d_in[29];
  const float* bout = (const float*)d_in[30];
  float* out = (float*)d_out;

  // workspace: xh | xl | Pb | Qb | xb | idx | sq | wph/wpl/wfh/wfl | wlb (~77.6 MB)
  float* base = (float*)d_ws;
  __bf16* xh = (__bf16*)base;
  __bf16* xl = (__bf16*)(base + 2097152);
  float* PbF = base + 4194304;
  float* QbF = PbF + 4194304;
  float* xbF = QbF + 4194304;
  int* idx = (int*)(xbF + 6291456);
  float* sq = (float*)(idx + 327680);
  __bf16* wph = (__bf16*)(sq + 65536);
  __bf16* wpl = (__bf16*)(sq + 65536 + 8192);
  __bf16* wfh = (__bf16*)(sq + 65536 + 16384);
  __bf16* wfl = (__bf16*)(sq + 65536 + 20480);
  __bf16* wlb = (__bf16*)(sq + 65536 + 24576);
  __bf16* Pb = (__bf16*)PbF;
  __bf16* Qb = (__bf16*)QbF;
  __bf16* xb = (__bf16*)xbF;
  float* uR = PbF;                                // alias (dead until k_mid's pq)
  float* vR = QbF;
  float* pool_part = base + 131072;               // in xh region: dead by linl
  float* p_pool = base + 1179648;                 // 32x1024 f32, after pool_part (xh region)
  float* h1g = base + 1212416;                    // 32x512 f32 (xh region)

  k_front<<<3180, 256, 0, stream>>>(pos, w1a, b1a, w1b, w1c, w2, wl, idx, uR, vR,
                                    wfh, wfl, wph, wpl, wlb);
  k_edge1<<<1024, 256, 0, stream>>>(idx, uR, vR, s1a, h1a, b1b, s1b, h1b, b1c,
                                    s1c, h1c, wfh, wfl, xh, xl, sq, xb);
  k_mid<<<2048, 512, 0, stream>>>(xh, xl, sq, idx, wph, wpl, Pb, Qb);
  k_gmax<<<8192, 256, 0, stream>>>(Pb, Qb, idx, b2, s2, h2, xb);
  k_linl_mfma<<<1024, 256, 0, stream>>>(xb, wlb, pool_part);
  k_pool<<<128, 256, 0, stream>>>(pool_part, bl, sl, hl, p_pool, out);
  k_m1<<<256, 256, 0, stream>>>(p_pool, wm1, bm1, sm1, hm1, h1g);
  k_m2o<<<128, 256, 0, stream>>>(h1g, wm2, bm2, sm2, hm2, wout, bout, out);
}

// Round 4
// 363.152 us; speedup vs baseline: 1.0326x; 1.0326x over previous
//
#include <hip/hip_runtime.h>

#define DEV __device__ __forceinline__
DEV float relu_(float x) { return fmaxf(x, 0.0f); }

typedef __attribute__((ext_vector_type(4))) float f32x4;
typedef __attribute__((ext_vector_type(8))) __bf16 bf16x8;

DEV unsigned short bfbits(__bf16 b) { union { unsigned short s; __bf16 b; } x; x.b = b; return x.s; }
DEV __bf16 bffrom(unsigned short s) { union { unsigned short s; __bf16 b; } x; x.s = s; return x.b; }

// branchy top-5 insert (wave-coherent merge streams + scalar merge kernel)
DEV void knn_insert(float (&bd)[5], int (&bi)[5], float d, int j) {
  if (d >= bd[4]) return;
  bd[4] = d; bi[4] = j;
#pragma unroll
  for (int p = 4; p > 0; --p) {
    if (bd[p] < bd[p - 1]) {
      float td = bd[p]; bd[p] = bd[p - 1]; bd[p - 1] = td;
      int ti = bi[p]; bi[p] = bi[p - 1]; bi[p - 1] = ti;
    }
  }
}

// branchless EXACT top-5 insert (used in knn1 tree merge)
DEV void knn_insert_bl(float (&bd)[5], int (&bi)[5], float d, int j) {
#pragma unroll
  for (int p = 0; p < 5; ++p) {
    bool lt = d < bd[p];
    float nd = lt ? d : bd[p];
    float cd = lt ? bd[p] : d;
    int ni = lt ? j : bi[p];
    int ci = lt ? bi[p] : j;
    bd[p] = nd; d = cd;
    bi[p] = ni; j = ci;
  }
}

// sorted top-5 insert via med3: new[i] = med3(old[i-1], old[i], x); new[0]=min.
// 5 VALU ops, no index tracking (index packed in low mantissa bits of x).
DEV void ins5(float (&b)[5], float x) {
  b[4] = __builtin_amdgcn_fmed3f(b[3], b[4], x);
  b[3] = __builtin_amdgcn_fmed3f(b[2], b[3], x);
  b[2] = __builtin_amdgcn_fmed3f(b[1], b[2], x);
  b[1] = __builtin_amdgcn_fmed3f(b[0], b[1], x);
  b[0] = fminf(b[0], x);
}

// ---------------- Kernel FRONT: knn1 (blk<2048) + uv (2048..3071) + preps (3072..3179) ----------------
__global__ __launch_bounds__(256) void k_front(
    const float* __restrict__ pos, const float* __restrict__ w1a,
    const float* __restrict__ b1a, const float* __restrict__ w1b,
    const float* __restrict__ w1c, const float* __restrict__ w2,
    const float* __restrict__ wl,
    int* __restrict__ idx1, float* __restrict__ uR, float* __restrict__ vR,
    __bf16* __restrict__ wfh, __bf16* __restrict__ wfl,
    __bf16* __restrict__ wph, __bf16* __restrict__ wpl,
    __bf16* __restrict__ wlb) {
  __shared__ __align__(16) float smem[9472];
  int tid = threadIdx.x;
  int blk = blockIdx.x;
  if (blk < 2048) {
    float* ps = smem;
    float* sqs = smem + 6144;
    float* md = smem + 8192;
    int* mi = (int*)(smem + 8832);
    int b = blk >> 6, qc = blk & 63;
    const float* src = pos + b * 6144;
    for (int u = tid; u < 6144; u += 256) ps[u] = src[u];
    __syncthreads();
    for (int u = tid; u < 2048; u += 256) {
      float x = ps[u * 3], y = ps[u * 3 + 1], z = ps[u * 3 + 2];
      sqs[u] = fmaf(z, z, fmaf(y, y, x * x));
    }
    __syncthreads();
    int q = tid & 31, sub = tid >> 5;
    int qi = qc * 32 + q;
    float qx = ps[qi * 3], qy = ps[qi * 3 + 1], qz = ps[qi * 3 + 2];
    float qsq = sqs[qi];
    // packed scan: idx (8 bits, j-j0) lives in low mantissa bits of d
    float bp[5] = {1e30f, 1e30f, 1e30f, 1e30f, 1e30f};
    int j0 = sub * 256;
    for (int j = j0; j < j0 + 256; ++j) {
      float px = ps[j * 3], py = ps[j * 3 + 1], pz = ps[j * 3 + 2];
      float dot = fmaf(qz, pz, fmaf(qy, py, qx * px));
      float d = fmaxf((qsq + sqs[j]) - 2.0f * dot, 0.0f);
      unsigned u = (__float_as_uint(d) & 0xFFFFFF00u) | (unsigned)(j & 255);
      ins5(bp, __uint_as_float(u));
    }
    float bd[5]; int bi[5];
#pragma unroll
    for (int k = 0; k < 5; ++k) {
      unsigned u = __float_as_uint(bp[k]);
      bd[k] = __uint_as_float(u & 0xFFFFFF00u);
      bi[k] = j0 + (int)(u & 255u);
    }
    for (int half = 4; half >= 1; half >>= 1) {
      __syncthreads();
      if (sub >= half && sub < 2 * half) {
        int slot = (q * 4 + (sub - half)) * 5;
#pragma unroll
        for (int k = 0; k < 5; ++k) { md[slot + k] = bd[k]; mi[slot + k] = bi[k]; }
      }
      __syncthreads();
      if (sub < half) {
        int slot = (q * 4 + sub) * 5;
#pragma unroll
        for (int k = 0; k < 5; ++k) knn_insert_bl(bd, bi, md[slot + k], mi[slot + k]);
      }
    }
    if (sub == 0) {
      int* op = idx1 + (b * 2048 + qi) * 5;
#pragma unroll
      for (int k = 0; k < 5; ++k) op[k] = bi[k];
    }
  } else if (blk < 3072) {
    float* wAs = smem;
    float* bs = smem + 384;
    float* uS = smem + 448;
    float* vS = smem + 4800;
    for (int u = tid; u < 384; u += 256) wAs[u] = w1a[u];
    if (tid < 64) bs[tid] = b1a[tid];
    __syncthreads();
    int lane = tid & 63, fq = tid >> 6;
    int p0 = (blk - 2048) * 64;
    int p = p0 + lane;
    float x0 = pos[p * 3], x1 = pos[p * 3 + 1], x2 = pos[p * 3 + 2];
#pragma unroll
    for (int m = 0; m < 16; ++m) {
      int f = fq * 16 + m;
      float wt0 = wAs[f], wt1 = wAs[64 + f], wt2 = wAs[128 + f];
      float wb0 = wAs[192 + f], wb1 = wAs[256 + f], wb2 = wAs[320 + f];
      float uval = bs[f];
      uval = fmaf(x0, wt0 - wb0, uval);
      uval = fmaf(x1, wt1 - wb1, uval);
      uval = fmaf(x2, wt2 - wb2, uval);
      uS[lane * 68 + f] = uval;
      vS[lane * 68 + f] = fmaf(x2, wb2, fmaf(x1, wb1, x0 * wb0));
    }
    __syncthreads();
#pragma unroll
    for (int it = 0; it < 4; ++it) {
      int g = it * 1024 + tid * 4;
      int pl = g >> 6, f = g & 63;
      float4 uu = *(const float4*)(uS + pl * 68 + f);
      float4 vv = *(const float4*)(vS + pl * 68 + f);
      *(float4*)(uR + (size_t)p0 * 64 + g) = uu;
      *(float4*)(vR + (size_t)p0 * 64 + g) = vv;
    }
  } else {
    int pblk = blk - 3072;
    if (pblk < 4) {
      int t = pblk * 256 + tid;
      int m = t >> 9;
      int rem = t & 511;
      int nb = rem >> 7;
      int rem2 = rem & 127;
      int s = rem2 >> 6, lane = rem2 & 63;
      int k0 = s * 32 + (lane >> 4) * 8;
      int c = nb * 16 + (lane & 15);
      const float* W = m ? w1c : w1b;
      __bf16 oh[8], ol[8];
#pragma unroll
      for (int j = 0; j < 8; ++j) {
        float val = W[(k0 + j) * 64 + c];
        __bf16 h = (__bf16)val;
        oh[j] = h;
        ol[j] = (__bf16)(val - (float)h);
      }
      size_t off = (size_t)m * 4096 + ((size_t)((nb * 2 + s) * 64 + lane)) * 8;
      *(uint4*)(wfh + off) = *(const uint4*)oh;
      *(uint4*)(wfl + off) = *(const uint4*)ol;
    } else if (pblk < 12) {
      int t = (pblk - 4) * 256 + tid;
      int nb = t >> 7;
      int rem = t & 127;
      int ks = rem >> 6, lane = rem & 63;
      int k0 = ks * 32 + (lane >> 4) * 8;
      int col16 = lane & 15;
      __bf16 oh[8], ol[8];
#pragma unroll
      for (int j = 0; j < 8; ++j) {
        int k = k0 + j;
        float val;
        if (nb < 8) {
          int c = nb * 16 + col16;
          val = w2[k * 128 + c] - w2[(64 + k) * 128 + c];
        } else {
          int c = (nb - 8) * 16 + col16;
          val = w2[(64 + k) * 128 + c];
        }
        __bf16 h = (__bf16)val;
        oh[j] = h;
        ol[j] = (__bf16)(val - (float)h);
      }
      *(uint4*)(wph + (size_t)t * 8) = *(const uint4*)oh;
      *(uint4*)(wpl + (size_t)t * 8) = *(const uint4*)ol;
    } else {
      int t = (pblk - 12) * 256 + tid;
      int nt = t / 3072;
      int rem = t - nt * 3072;
      int ks = rem / 512;
      int rem2 = rem - ks * 512;
      int nb = rem2 >> 6, lane = rem2 & 63;
      int k0 = ks * 32 + (lane >> 4) * 8;
      int n = nt * 128 + nb * 16 + (lane & 15);
      __bf16 o[8];
#pragma unroll
      for (int j = 0; j < 8; ++j) o[j] = (__bf16)wl[(k0 + j) * 1024 + n];
      *(uint4*)(wlb + (size_t)t * 8) = *(const uint4*)o;
    }
  }
}

// ---------------- Kernel 2: EdgeConv1 layers 2/3 via hi/lo MFMA, barrier-free k-loop ----------------
__global__ __launch_bounds__(256) void k_edge1(
    const int* __restrict__ idx1, const float* __restrict__ uR,
    const float* __restrict__ vR,
    const float* __restrict__ s1a, const float* __restrict__ h1a,
    const float* __restrict__ b1b, const float* __restrict__ s1b,
    const float* __restrict__ h1b,
    const float* __restrict__ b1c, const float* __restrict__ s1c,
    const float* __restrict__ h1c,
    const __bf16* __restrict__ wfh, const __bf16* __restrict__ wfl,
    __bf16* __restrict__ xh, __bf16* __restrict__ xl,
    float* __restrict__ sqo, __bf16* __restrict__ xb) {
  __shared__ __align__(16) __bf16 Wh[8192], Wl[8192];
  __shared__ __align__(16) unsigned h2b[4 * 1088];
  int tid = threadIdx.x;
  int w = tid >> 6, lane = tid & 63;
  int quad = lane >> 4, lm = lane & 15;
#pragma unroll
  for (int it = 0; it < 4; ++it) {
    int u4 = it * 256 + tid;
    *(uint4*)(Wh + (size_t)u4 * 8) = *(const uint4*)(wfh + (size_t)u4 * 8);
    *(uint4*)(Wl + (size_t)u4 * 8) = *(const uint4*)(wfl + (size_t)u4 * 8);
  }
  int p0 = blockIdx.x * 64;
  int b = p0 >> 11;
  size_t bb = (size_t)b * 2048;
  int edge = p0 + w * 16 + lm;
  float sA[2][8], hA[2][8];
#pragma unroll
  for (int s = 0; s < 2; ++s)
#pragma unroll
    for (int j = 0; j < 8; ++j) {
      int k = s * 32 + quad * 8 + j;
      sA[s][j] = s1a[k]; hA[s][j] = h1a[k];
    }
  float bB[4], sB[4], hB[4], bC[4], sC[4], hC[4];
#pragma unroll
  for (int nb = 0; nb < 4; ++nb) {
    int c = nb * 16 + lm;
    bB[nb] = b1b[c]; sB[nb] = s1b[c]; hB[nb] = h1b[c];
    bC[nb] = b1c[c]; sC[nb] = s1c[c]; hC[nb] = h1c[c];
  }
  unsigned* h2w = h2b + w * 1088;
  f32x4 mmax[4];
#pragma unroll
  for (int nb = 0; nb < 4; ++nb)
    mmax[nb] = (f32x4){-3.4e38f, -3.4e38f, -3.4e38f, -3.4e38f};
  __syncthreads();
  const float* urow = uR + (size_t)edge * 64;
  for (int kk = 0; kk < 5; ++kk) {
    int jn = idx1[edge * 5 + kk];
    const float* vrow = vR + (bb + jn) * 64;
    bf16x8 Ah[2], Al[2];
#pragma unroll
    for (int s = 0; s < 2; ++s) {
      int off = s * 32 + quad * 8;
      float4 u0 = *(const float4*)(urow + off);
      float4 u1 = *(const float4*)(urow + off + 4);
      float4 v0 = *(const float4*)(vrow + off);
      float4 v1 = *(const float4*)(vrow + off + 4);
      float uv[8] = {u0.x + v0.x, u0.y + v0.y, u0.z + v0.z, u0.w + v0.w,
                     u1.x + v1.x, u1.y + v1.y, u1.z + v1.z, u1.w + v1.w};
      __bf16 th[8], tl[8];
#pragma unroll
      for (int j = 0; j < 8; ++j) {
        float val = relu_(uv[j]) * sA[s][j] + hA[s][j];
        __bf16 hb = (__bf16)val;
        th[j] = hb;
        tl[j] = (__bf16)(val - (float)hb);
      }
      Ah[s] = *(const bf16x8*)th;
      Al[s] = *(const bf16x8*)tl;
    }
#pragma unroll
    for (int nb = 0; nb < 4; ++nb) {
      bf16x8 Bh0 = *(const bf16x8*)(Wh + ((size_t)((nb * 2 + 0) * 64 + lane)) * 8);
      bf16x8 Bh1 = *(const bf16x8*)(Wh + ((size_t)((nb * 2 + 1) * 64 + lane)) * 8);
      bf16x8 Bl0 = *(const bf16x8*)(Wl + ((size_t)((nb * 2 + 0) * 64 + lane)) * 8);
      bf16x8 Bl1 = *(const bf16x8*)(Wl + ((size_t)((nb * 2 + 1) * 64 + lane)) * 8);
      f32x4 a2 = {0.f, 0.f, 0.f, 0.f};
      a2 = __builtin_amdgcn_mfma_f32_16x16x32_bf16(Ah[0], Bh0, a2, 0, 0, 0);
      a2 = __builtin_amdgcn_mfma_f32_16x16x32_bf16(Ah[1], Bh1, a2, 0, 0, 0);
      a2 = __builtin_amdgcn_mfma_f32_16x16x32_bf16(Ah[0], Bl0, a2, 0, 0, 0);
      a2 = __builtin_amdgcn_mfma_f32_16x16x32_bf16(Ah[1], Bl1, a2, 0, 0, 0);
      a2 = __builtin_amdgcn_mfma_f32_16x16x32_bf16(Al[0], Bh0, a2, 0, 0, 0);
      a2 = __builtin_amdgcn_mfma_f32_16x16x32_bf16(Al[1], Bh1, a2, 0, 0, 0);
#pragma unroll
      for (int r = 0; r < 4; ++r) {
        float vv2 = relu_(a2[r] + bB[nb]) * sB[nb] + hB[nb];
        __bf16 hb = (__bf16)vv2;
        __bf16 lb = (__bf16)(vv2 - (float)hb);
        h2w[(quad * 4 + r) * 68 + nb * 16 + lm] =
            (unsigned)bfbits(hb) | ((unsigned)bfbits(lb) << 16);
      }
    }
    bf16x8 A3h[2], A3l[2];
#pragma unroll
    for (int s = 0; s < 2; ++s) {
      const unsigned* rp = h2w + lm * 68 + s * 32 + quad * 8;
      uint4 da = *(const uint4*)rp;
      uint4 db = *(const uint4*)(rp + 4);
      unsigned dw[8] = {da.x, da.y, da.z, da.w, db.x, db.y, db.z, db.w};
      __bf16 th[8], tl[8];
#pragma unroll
      for (int j = 0; j < 8; ++j) {
        th[j] = bffrom((unsigned short)(dw[j] & 0xFFFFu));
        tl[j] = bffrom((unsigned short)(dw[j] >> 16));
      }
      A3h[s] = *(const bf16x8*)th;
      A3l[s] = *(const bf16x8*)tl;
    }
#pragma unroll
    for (int nb = 0; nb < 4; ++nb) {
      bf16x8 Bh0 = *(const bf16x8*)(Wh + 4096 + ((size_t)((nb * 2 + 0) * 64 + lane)) * 8);
      bf16x8 Bh1 = *(const bf16x8*)(Wh + 4096 + ((size_t)((nb * 2 + 1) * 64 + lane)) * 8);
      bf16x8 Bl0 = *(const bf16x8*)(Wl + 4096 + ((size_t)((nb * 2 + 0) * 64 + lane)) * 8);
      bf16x8 Bl1 = *(const bf16x8*)(Wl + 4096 + ((size_t)((nb * 2 + 1) * 64 + lane)) * 8);
      f32x4 a3 = {0.f, 0.f, 0.f, 0.f};
      a3 = __builtin_amdgcn_mfma_f32_16x16x32_bf16(A3h[0], Bh0, a3, 0, 0, 0);
      a3 = __builtin_amdgcn_mfma_f32_16x16x32_bf16(A3h[1], Bh1, a3, 0, 0, 0);
      a3 = __builtin_amdgcn_mfma_f32_16x16x32_bf16(A3h[0], Bl0, a3, 0, 0, 0);
      a3 = __builtin_amdgcn_mfma_f32_16x16x32_bf16(A3h[1], Bl1, a3, 0, 0, 0);
      a3 = __builtin_amdgcn_mfma_f32_16x16x32_bf16(A3l[0], Bh0, a3, 0, 0, 0);
      a3 = __builtin_amdgcn_mfma_f32_16x16x32_bf16(A3l[1], Bh1, a3, 0, 0, 0);
#pragma unroll
      for (int r = 0; r < 4; ++r) mmax[nb][r] = fmaxf(mmax[nb][r], a3[r]);
    }
  }
  float sqp[4] = {0.f, 0.f, 0.f, 0.f};
#pragma unroll
  for (int nb = 0; nb < 4; ++nb) {
    int c = nb * 16 + lm;
#pragma unroll
    for (int r = 0; r < 4; ++r) {
      float vv3 = relu_(mmax[nb][r] + bC[nb]) * sC[nb] + hC[nb];
      sqp[r] = fmaf(vv3, vv3, sqp[r]);
      __bf16 hb = (__bf16)vv3;
      __bf16 lb = (__bf16)(vv3 - (float)hb);
      int n = p0 + w * 16 + quad * 4 + r;
      xh[(size_t)n * 64 + c] = hb;
      xl[(size_t)n * 64 + c] = lb;
      xb[(size_t)n * 192 + c] = hb;
    }
  }
#pragma unroll
  for (int r = 0; r < 4; ++r) {
    float s = sqp[r];
    s += __shfl_xor(s, 1);
    s += __shfl_xor(s, 2);
    s += __shfl_xor(s, 4);
    s += __shfl_xor(s, 8);
    if (lm == 0) sqo[p0 + w * 16 + quad * 4 + r] = s;
  }
}

// ---------------- Kernel MID: knn2 half-scan (blk<2048) + pq_mfma (2048..3071) ----------------
// 256 thr, 26.6KB LDS (6 blocks/CU). knn2 split by candidate half across 2 blocks:
// block (qc,g) scans candidates [g*1024,(g+1)*1024), writes exact top-5 partial into
// the dead xb stripe (ch 64..191, overwritten later by k_gmax). k_kmerge merges.
__global__ __launch_bounds__(256) void k_mid(const __bf16* __restrict__ xh,
                                             const __bf16* __restrict__ xl,
                                             const float* __restrict__ sq,
                                             __bf16* __restrict__ scratch,
                                             const __bf16* __restrict__ wph,
                                             const __bf16* __restrict__ wpl,
                                             __bf16* __restrict__ Pb,
                                             __bf16* __restrict__ Qb) {
  __shared__ __align__(16) float smem[6656];
  int tid = threadIdx.x;
  int w = tid >> 6, lane = tid & 63;
  int quad = lane >> 4, lm = lane & 15;
  if (blockIdx.x < 2048) {
    __bf16* Bh = (__bf16*)smem;
    __bf16* Bl = (__bf16*)(smem + 2304);
    float* sqs = smem + 4608;
    int blk = blockIdx.x;
    int b = blk >> 6;
    int w6 = blk & 63;
    int qc = w6 >> 1, g = w6 & 1;
    int q0 = qc * 64;
    size_t bb = (size_t)b * 2048;
    for (int u = tid; u < 512; u += 256)
      *(float4*)(sqs + u * 4) = *(const float4*)(sq + bb + u * 4);
    const __bf16* qh = xh + (bb + q0 + w * 16 + lm) * 64 + quad * 8;
    const __bf16* ql = xl + (bb + q0 + w * 16 + lm) * 64 + quad * 8;
    bf16x8 Ah0 = *(const bf16x8*)(qh);
    bf16x8 Ah1 = *(const bf16x8*)(qh + 32);
    bf16x8 Al0 = *(const bf16x8*)(ql);
    bf16x8 Al1 = *(const bf16x8*)(ql + 32);
    __syncthreads();
    float qsq[4];
#pragma unroll
    for (int r = 0; r < 4; ++r) qsq[r] = sqs[q0 + w * 16 + quad * 4 + r];
    // packed scan: key6 = it*4+nt (6 bits) in low mantissa bits; lm + g implicit
    float bp[4][5];
#pragma unroll
    for (int r = 0; r < 4; ++r)
#pragma unroll
      for (int k = 0; k < 5; ++k) bp[r][k] = 1e30f;
    for (int it = 0; it < 16; ++it) {
      int ct = g * 16 + it;
#pragma unroll
      for (int pass = 0; pass < 2; ++pass) {
        int unit = pass * 256 + tid;
        int n = unit >> 3, cc = unit & 7;
        const __bf16* gsrc = xh + (bb + ct * 64 + n) * 64 + cc * 8;
        const __bf16* gsrl = xl + (bb + ct * 64 + n) * 64 + cc * 8;
        *(uint4*)(Bh + n * 72 + cc * 8) = *(const uint4*)gsrc;
        *(uint4*)(Bl + n * 72 + cc * 8) = *(const uint4*)gsrl;
      }
      __syncthreads();
#pragma unroll
      for (int nt = 0; nt < 4; ++nt) {
        const __bf16* bph = Bh + (nt * 16 + lm) * 72 + quad * 8;
        const __bf16* bpl = Bl + (nt * 16 + lm) * 72 + quad * 8;
        bf16x8 Bh0 = *(const bf16x8*)(bph);
        bf16x8 Bh1 = *(const bf16x8*)(bph + 32);
        bf16x8 Bl0 = *(const bf16x8*)(bpl);
        bf16x8 Bl1 = *(const bf16x8*)(bpl + 32);
        f32x4 acc = {0.f, 0.f, 0.f, 0.f};
        acc = __builtin_amdgcn_mfma_f32_16x16x32_bf16(Ah0, Bh0, acc, 0, 0, 0);
        acc = __builtin_amdgcn_mfma_f32_16x16x32_bf16(Ah1, Bh1, acc, 0, 0, 0);
        acc = __builtin_amdgcn_mfma_f32_16x16x32_bf16(Ah0, Bl0, acc, 0, 0, 0);
        acc = __builtin_amdgcn_mfma_f32_16x16x32_bf16(Ah1, Bl1, acc, 0, 0, 0);
        acc = __builtin_amdgcn_mfma_f32_16x16x32_bf16(Al0, Bh0, acc, 0, 0, 0);
        acc = __builtin_amdgcn_mfma_f32_16x16x32_bf16(Al1, Bh1, acc, 0, 0, 0);
        float csq = sqs[ct * 64 + nt * 16 + lm];
        unsigned key = (unsigned)(it * 4 + nt);
#pragma unroll
        for (int r = 0; r < 4; ++r) {
          float d = fmaxf((qsq[r] + csq) - 2.0f * acc[r], 0.0f);
          unsigned u = (__float_as_uint(d) & 0xFFFFFFC0u) | key;
          ins5(bp[r], __uint_as_float(u));
        }
      }
      __syncthreads();
    }
    float bd[4][5];
    int bi[4][5];
#pragma unroll
    for (int r = 0; r < 4; ++r)
#pragma unroll
      for (int k = 0; k < 5; ++k) {
        unsigned u = __float_as_uint(bp[r][k]);
        bd[r][k] = __uint_as_float(u & 0xFFFFFFC0u);
        bi[r][k] = (g << 10) + (((int)(u & 63u)) << 4) + lm;
      }
    // exact wave merge across the 16 lm lanes of each quad
    for (int m = 1; m <= 8; m <<= 1) {
#pragma unroll
      for (int r = 0; r < 4; ++r) {
        float od[5]; int oi[5];
#pragma unroll
        for (int k = 0; k < 5; ++k) {
          od[k] = __shfl_xor(bd[r][k], m);
          oi[k] = __shfl_xor(bi[r][k], m);
        }
#pragma unroll
        for (int k = 0; k < 5; ++k) knn_insert(bd[r], bi[r], od[k], oi[k]);
      }
    }
    if (lm == 0) {
#pragma unroll
      for (int r = 0; r < 4; ++r) {
        int qi = q0 + w * 16 + quad * 4 + r;
        uint2* sp = (uint2*)((char*)scratch + (size_t)(bb + qi) * 384 + 128 + g * 40);
#pragma unroll
        for (int k = 0; k < 5; ++k) {
          uint2 v;
          v.x = __float_as_uint(bd[r][k]);
          v.y = (unsigned)bi[r][k];
          sp[k] = v;
        }
      }
    }
  } else {
    __bf16* Wh = (__bf16*)smem;
    __bf16* Wl = (__bf16*)(smem + 2048);
    int n0 = (blockIdx.x - 2048) * 64;
    const __bf16* ah = xh + (size_t)(n0 + w * 16 + lm) * 64 + quad * 8;
    const __bf16* al = xl + (size_t)(n0 + w * 16 + lm) * 64 + quad * 8;
    bf16x8 Ah0 = *(const bf16x8*)(ah);
    bf16x8 Ah1 = *(const bf16x8*)(ah + 32);
    bf16x8 Al0 = *(const bf16x8*)(al);
    bf16x8 Al1 = *(const bf16x8*)(al + 32);
    for (int chunk = 0; chunk < 4; ++chunk) {
      __syncthreads();
#pragma unroll
      for (int it = 0; it < 2; ++it) {
        int unit = it * 256 + tid;
        *(uint4*)(Wh + (size_t)unit * 8) =
            *(const uint4*)(wph + (size_t)chunk * 4096 + (size_t)unit * 8);
        *(uint4*)(Wl + (size_t)unit * 8) =
            *(const uint4*)(wpl + (size_t)chunk * 4096 + (size_t)unit * 8);
      }
      __syncthreads();
#pragma unroll
      for (int nb4 = 0; nb4 < 4; ++nb4) {
        int nb = chunk * 4 + nb4;
        bf16x8 Bh0 = *(const bf16x8*)(Wh + ((size_t)(nb4 * 2 + 0) * 64 + lane) * 8);
        bf16x8 Bh1 = *(const bf16x8*)(Wh + ((size_t)(nb4 * 2 + 1) * 64 + lane) * 8);
        bf16x8 Bl0 = *(const bf16x8*)(Wl + ((size_t)(nb4 * 2 + 0) * 64 + lane) * 8);
        bf16x8 Bl1 = *(const bf16x8*)(Wl + ((size_t)(nb4 * 2 + 1) * 64 + lane) * 8);
        f32x4 acc = {0.f, 0.f, 0.f, 0.f};
        acc = __builtin_amdgcn_mfma_f32_16x16x32_bf16(Ah0, Bh0, acc, 0, 0, 0);
        acc = __builtin_amdgcn_mfma_f32_16x16x32_bf16(Ah1, Bh1, acc, 0, 0, 0);
        acc = __builtin_amdgcn_mfma_f32_16x16x32_bf16(Ah0, Bl0, acc, 0, 0, 0);
        acc = __builtin_amdgcn_mfma_f32_16x16x32_bf16(Ah1, Bl1, acc, 0, 0, 0);
        acc = __builtin_amdgcn_mfma_f32_16x16x32_bf16(Al0, Bh0, acc, 0, 0, 0);
        acc = __builtin_amdgcn_mfma_f32_16x16x32_bf16(Al1, Bh1, acc, 0, 0, 0);
        bool isP = (nb < 8);
        __bf16* base = isP ? Pb : Qb;
        int col = (isP ? nb : nb - 8) * 16 + lm;
#pragma unroll
        for (int r = 0; r < 4; ++r) {
          int n = n0 + w * 16 + quad * 4 + r;
          base[(size_t)n * 128 + col] = (__bf16)acc[r];
        }
      }
    }
  }
}

// ---------------- Kernel MERGE: combine the two candidate-half top-5 partials -> idx2 ----------------
// grid 256 x 256 thr: 1 query/thread. g0 cids < g1 cids; strict-< insert keeps lower-index ties.
__global__ __launch_bounds__(256) void k_kmerge(const __bf16* __restrict__ scratch,
                                                int* __restrict__ idx2) {
  int n = blockIdx.x * 256 + threadIdx.x;
  const uint2* sp = (const uint2*)((const char*)scratch + (size_t)n * 384 + 128);
  float bd[5]; int bi[5];
#pragma unroll
  for (int k = 0; k < 5; ++k) {
    uint2 v = sp[k];
    bd[k] = __uint_as_float(v.x);
    bi[k] = (int)v.y;
  }
#pragma unroll
  for (int k = 0; k < 5; ++k) {
    uint2 v = sp[5 + k];
    knn_insert(bd, bi, __uint_as_float(v.x), (int)v.y);
  }
  int* op = idx2 + (size_t)n * 5;
#pragma unroll
  for (int k = 0; k < 5; ++k) op[k] = bi[k];
}

// ---------------- Kernel 4b: gather-max + activation, 4 channels/lane ----------------
// grid 8192 (8 points/block); per-channel math order identical (bit-exact)
__global__ __launch_bounds__(256) void k_gmax(const __bf16* __restrict__ Pb,
                                              const __bf16* __restrict__ Qb,
                                              const int* __restrict__ idx2,
                                              const float* __restrict__ b2,
                                              const float* __restrict__ s2,
                                              const float* __restrict__ h2v,
                                              __bf16* __restrict__ xb) {
  int tid = threadIdx.x;
  int c4 = tid & 31, p = tid >> 5;  // 32 lanes/point, 8 points/block
  int n = blockIdx.x * 8 + p;
  int b = n >> 11;
  const int* ip = idx2 + n * 5;
  int c0 = c4 * 4;
  float m[4] = {-3.4e38f, -3.4e38f, -3.4e38f, -3.4e38f};
#pragma unroll
  for (int k = 0; k < 5; ++k) {
    int j = ip[k];
    uint2 q = *(const uint2*)(Qb + ((size_t)(b * 2048 + j)) * 128 + c0);
    m[0] = fmaxf(m[0], (float)bffrom((unsigned short)(q.x & 0xFFFFu)));
    m[1] = fmaxf(m[1], (float)bffrom((unsigned short)(q.x >> 16)));
    m[2] = fmaxf(m[2], (float)bffrom((unsigned short)(q.y & 0xFFFFu)));
    m[3] = fmaxf(m[3], (float)bffrom((unsigned short)(q.y >> 16)));
  }
  uint2 pv = *(const uint2*)(Pb + (size_t)n * 128 + c0);
  float pvf[4] = {(float)bffrom((unsigned short)(pv.x & 0xFFFFu)),
                  (float)bffrom((unsigned short)(pv.x >> 16)),
                  (float)bffrom((unsigned short)(pv.y & 0xFFFFu)),
                  (float)bffrom((unsigned short)(pv.y >> 16))};
  __bf16 o[4];
#pragma unroll
  for (int i = 0; i < 4; ++i) {
    float v = pvf[i] + m[i] + b2[c0 + i];
    o[i] = (__bf16)(relu_(v) * s2[c0 + i] + h2v[c0 + i]);
  }
  uint2 ov;
  ov.x = (unsigned)bfbits(o[0]) | ((unsigned)bfbits(o[1]) << 16);
  ov.y = (unsigned)bfbits(o[2]) | ((unsigned)bfbits(o[3]) << 16);
  *(uint2*)(xb + (size_t)n * 192 + 64 + c0) = ov;
}

// ---------------- Kernel 5: bf16 MFMA GEMM fused point-max, A staged once, ng loop ----------------
// grid 1024 (mg); LDS: Aall 24KB + B chunk 16KB = 40KB -> 4 blocks/CU (= grid/256CU)
__global__ __launch_bounds__(256) void k_linl_mfma(const __bf16* __restrict__ xb,
                                                   const __bf16* __restrict__ wlb,
                                                   float* __restrict__ pool_part) {
  __shared__ __align__(16) __bf16 Aall[12288];  // [mb4][ks6][lane64][8]
  __shared__ __align__(16) __bf16 Bl[8192];     // [nt2][nb8][lane64][8]
  int tid = threadIdx.x;
  int w = tid >> 6, lane = tid & 63;
  int mg = blockIdx.x;
  int n0 = mg << 6;
  int quad = lane >> 4, lm = lane & 15;
  // stage ALL of this mg's A-tile once (1536 uint4)
#pragma unroll
  for (int it = 0; it < 6; ++it) {
    int unit = it * 256 + tid;           // 0..1535
    int mb = unit / 384;
    int rem = unit - mb * 384;
    int ks = rem >> 6, ln = rem & 63;
    int lmm = ln & 15, qd = ln >> 4;
    const uint4* ga = (const uint4*)(xb + (size_t)(n0 + mb * 16 + lmm) * 192 + ks * 32 + qd * 8);
    *(uint4*)(Aall + ((size_t)(mb * 6 + ks) * 64 + ln) * 8) = *ga;
  }
  for (int ng = 0; ng < 4; ++ng) {
    f32x4 acc[4][4];
#pragma unroll
    for (int i = 0; i < 4; ++i)
#pragma unroll
      for (int j = 0; j < 4; ++j) acc[i][j] = (f32x4){0.f, 0.f, 0.f, 0.f};
    for (int ks = 0; ks < 6; ++ks) {
      __syncthreads();  // protect prev B reads (and covers initial A staging)
#pragma unroll
      for (int nt2 = 0; nt2 < 2; ++nt2) {
#pragma unroll
        for (int u = 0; u < 2; ++u) {
          int unit = u * 256 + tid;
          const uint4* gb = (const uint4*)(wlb + ((size_t)((ng * 2 + nt2) * 6 + ks)) * 4096 + (size_t)unit * 8);
          *(uint4*)(Bl + (size_t)nt2 * 4096 + (size_t)unit * 8) = *gb;
        }
      }
      __syncthreads();
      bf16x8 af[4], bfr[4];
#pragma unroll
      for (int i = 0; i < 4; ++i)
        af[i] = *(const bf16x8*)(Aall + ((size_t)(i * 6 + ks) * 64 + lane) * 8);
      int nt2 = w >> 1, nbb = (w & 1) * 4;
#pragma unroll
      for (int j = 0; j < 4; ++j)
        bfr[j] = *(const bf16x8*)(Bl + (size_t)nt2 * 4096 + ((size_t)((nbb + j) * 64 + lane)) * 8);
#pragma unroll
      for (int i = 0; i < 4; ++i)
#pragma unroll
        for (int j = 0; j < 4; ++j)
          acc[i][j] = __builtin_amdgcn_mfma_f32_16x16x32_bf16(af[i], bfr[j], acc[i][j], 0, 0, 0);
    }
#pragma unroll
    for (int j = 0; j < 4; ++j) {
      float m = -3.4e38f;
#pragma unroll
      for (int i = 0; i < 4; ++i)
#pragma unroll
        for (int r = 0; r < 4; ++r) m = fmaxf(m, acc[i][j][r]);
      m = fmaxf(m, __shfl_xor(m, 16));
      m = fmaxf(m, __shfl_xor(m, 32));
      if (quad == 0) {
        int ch = ng * 256 + (w >> 1) * 128 + (w & 1) * 64 + j * 16 + lm;
        pool_part[(size_t)mg * 1024 + ch] = m;
      }
    }
  }
}

// ---------------- Kernel 6a: pool merge (32-way max) + lin/bn -> p[32][1024]; zeroes out ----------------
// grid 128 (32 b x 4 cblk), 256 thr: 1 channel/thread, 32 strided loads w/ 4-way ILP
__global__ __launch_bounds__(256) void k_pool(const float* __restrict__ pool_part,
                                              const float* __restrict__ bl,
                                              const float* __restrict__ sl,
                                              const float* __restrict__ hl,
                                              float* __restrict__ p,
                                              float* __restrict__ out) {
  int b = blockIdx.x >> 2, cb = blockIdx.x & 3;
  int c = cb * 256 + threadIdx.x;
  const float* src = pool_part + (size_t)(b * 32) * 1024 + c;
  float m0 = -3.4e38f, m1 = -3.4e38f, m2 = -3.4e38f, m3 = -3.4e38f;
#pragma unroll
  for (int t = 0; t < 32; t += 4) {
    m0 = fmaxf(m0, src[(size_t)t * 1024]);
    m1 = fmaxf(m1, src[(size_t)(t + 1) * 1024]);
    m2 = fmaxf(m2, src[(size_t)(t + 2) * 1024]);
    m3 = fmaxf(m3, src[(size_t)(t + 3) * 1024]);
  }
  float m = fmaxf(fmaxf(m0, m1), fmaxf(m2, m3));
  p[b * 1024 + c] = relu_(m + bl[c]) * sl[c] + hl[c];
  if (blockIdx.x == 0 && threadIdx.x < 64) out[threadIdx.x] = 0.0f;
}

// ---------------- Kernel 6b: h1 = act(p @ wm1) ----------------
// grid 256 (32 b x 8 cblk), 256 thr: 4 waves split the 1024-deep f-dim, LDS reduce
__global__ __launch_bounds__(256) void k_m1(const float* __restrict__ p,
                                            const float* __restrict__ wm1,
                                            const float* __restrict__ bm1,
                                            const float* __restrict__ sm1,
                                            const float* __restrict__ hm1,
                                            float* __restrict__ h1) {
  __shared__ float p_s[1024];
  __shared__ float red[4][64];
  int b = blockIdx.x >> 3, cb = blockIdx.x & 7;
  int tid = threadIdx.x;
  for (int u = tid; u < 1024; u += 256) p_s[u] = p[b * 1024 + u];
  __syncthreads();
  int c64 = tid & 63, q = tid >> 6;
  int C = cb * 64 + c64;
  int f0 = q * 256;
  const float* W = wm1 + (size_t)f0 * 512 + C;
  float a[8] = {0.f, 0.f, 0.f, 0.f, 0.f, 0.f, 0.f, 0.f};
  for (int f = 0; f < 256; f += 8) {
#pragma unroll
    for (int u = 0; u < 8; ++u)
      a[u] = fmaf(p_s[f0 + f + u], W[(size_t)(f + u) * 512], a[u]);
  }
  red[q][c64] = ((a[0] + a[1]) + (a[2] + a[3])) + ((a[4] + a[5]) + (a[6] + a[7]));
  __syncthreads();
  if (tid < 64) {
    float t = (red[0][tid] + red[1][tid]) + (red[2][tid] + red[3][tid]);
    int C2 = cb * 64 + tid;
    h1[b * 512 + C2] = relu_(t + bm1[C2]) * sm1[C2] + hm1[C2];
  }
}

// ---------------- Kernel 6c: h2 = act(h1 @ wm2); out += h2-slice @ wout (atomic partials) ----------------
// grid 128 (32 b x 4 cblk), 256 thr
__global__ __launch_bounds__(256) void k_m2o(const float* __restrict__ h1,
                                             const float* __restrict__ wm2,
                                             const float* __restrict__ bm2,
                                             const float* __restrict__ sm2,
                                             const float* __restrict__ hm2,
                                             const float* __restrict__ wout,
                                             const float* __restrict__ bout,
                                             float* __restrict__ out) {
  __shared__ float h1_s[512];
  __shared__ float red[4][64];
  int b = blockIdx.x >> 2, cb = blockIdx.x & 3;
  int tid = threadIdx.x;
  for (int u = tid; u < 512; u += 256) h1_s[u] = h1[b * 512 + u];
  __syncthreads();
  int c64 = tid & 63, q = tid >> 6;
  int C = cb * 64 + c64;
  int f0 = q * 128;
  const float* W = wm2 + (size_t)f0 * 256 + C;
  float a[4] = {0.f, 0.f, 0.f, 0.f};
  for (int f = 0; f < 128; f += 4) {
#pragma unroll
    for (int u = 0; u < 4; ++u)
      a[u] = fmaf(h1_s[f0 + f + u], W[(size_t)(f + u) * 256], a[u]);
  }
  red[q][c64] = (a[0] + a[1]) + (a[2] + a[3]);
  __syncthreads();
  if (tid < 64) {
    float t = (red[0][tid] + red[1][tid]) + (red[2][tid] + red[3][tid]);
    int C2 = cb * 64 + tid;
    float h2v = relu_(t + bm2[C2]) * sm2[C2] + hm2[C2];
    float2 wv = *(const float2*)(wout + C2 * 2);
    float v0 = h2v * wv.x, v1 = h2v * wv.y;
#pragma unroll
    for (int m = 1; m < 64; m <<= 1) {
      v0 += __shfl_xor(v0, m);
      v1 += __shfl_xor(v1, m);
    }
    if (tid == 0) {
      if (cb == 0) { v0 += bout[0]; v1 += bout[1]; }
      atomicAdd(&out[b * 2], v0);
      atomicAdd(&out[b * 2 + 1], v1);
    }
  }
}

extern "C" void kernel_launch(void* const* d_in, const int* in_sizes, int n_in,
                              void* d_out, int out_size, void* d_ws, size_t ws_size,
                              hipStream_t stream) {
  const float* pos = (const float*)d_in[0];
  const float* w1a = (const float*)d_in[1];
  const float* b1a = (const float*)d_in[2];
  const float* s1a = (const float*)d_in[3];
  const float* h1a = (const float*)d_in[4];
  const float* w1b = (const float*)d_in[5];
  const float* b1b = (const float*)d_in[6];
  const float* s1b = (const float*)d_in[7];
  const float* h1b = (const float*)d_in[8];
  const float* w1c = (const float*)d_in[9];
  const float* b1c = (const float*)d_in[10];
  const float* s1c = (const float*)d_in[11];
  const float* h1c = (const float*)d_in[12];
  const float* w2 = (const float*)d_in[13];
  const float* b2 = (const float*)d_in[14];
  const float* s2 = (const float*)d_in[15];
  const float* h2 = (const float*)d_in[16];
  const float* wl = (const float*)d_in[17];
  const float* bl = (const float*)d_in[18];
  const float* sl = (const float*)d_in[19];
  const float* hl = (const float*)d_in[20];
  const float* wm1 = (const float*)d_in[21];
  const float* bm1 = (const float*)d_in[22];
  const float* sm1 = (const float*)d_in[23];
  const float* hm1 = (const float*)d_in[24];
  const float* wm2 = (const float*)d_in[25];
  const float* bm2 = (const float*)d_in[26];
  const float* sm2 = (const float*)d_in[27];
  const float* hm2 = (const float*)d_in[28];
  const float* wout = (const float*)d_in[29];
  const float* bout = (const float*)d_in[30];
  float* out = (float*)d_out;

  // workspace: xh | xl | Pb | Qb | xb | idx | sq | wph/wpl/wfh/wfl | wlb (~77.6 MB)
  float* base = (float*)d_ws;
  __bf16* xh = (__bf16*)base;
  __bf16* xl = (__bf16*)(base + 2097152);
  float* PbF = base + 4194304;
  float* QbF = PbF + 4194304;
  float* xbF = QbF + 4194304;
  int* idx = (int*)(xbF + 6291456);
  float* sq = (float*)(idx + 327680);
  __bf16* wph = (__bf16*)(sq + 65536);
  __bf16* wpl = (__bf16*)(sq + 65536 + 8192);
  __bf16* wfh = (__bf16*)(sq + 65536 + 16384);
  __bf16* wfl = (__bf16*)(sq + 65536 + 20480);
  __bf16* wlb = (__bf16*)(sq + 65536 + 24576);
  __bf16* Pb = (__bf16*)PbF;
  __bf16* Qb = (__bf16*)QbF;
  __bf16* xb = (__bf16*)xbF;
  float* uR = PbF;                                // alias (dead until k_mid's pq)
  float* vR = QbF;
  float* pool_part = base + 131072;               // in xh region: dead by linl
  float* p_pool = base + 1179648;                 // 32x1024 f32, after pool_part (xh region)
  float* h1g = base + 1212416;                    // 32x512 f32 (xh region)

  k_front<<<3180, 256, 0, stream>>>(pos, w1a, b1a, w1b, w1c, w2, wl, idx, uR, vR,
                                    wfh, wfl, wph, wpl, wlb);
  k_edge1<<<1024, 256, 0, stream>>>(idx, uR, vR, s1a, h1a, b1b, s1b, h1b, b1c,
                                    s1c, h1c, wfh, wfl, xh, xl, sq, xb);
  k_mid<<<3072, 256, 0, stream>>>(xh, xl, sq, xb, wph, wpl, Pb, Qb);
  k_kmerge<<<256, 256, 0, stream>>>(xb, idx);
  k_gmax<<<8192, 256, 0, stream>>>(Pb, Qb, idx, b2, s2, h2, xb);
  k_linl_mfma<<<1024, 256, 0, stream>>>(xb, wlb, pool_part);
  k_pool<<<128, 256, 0, stream>>>(pool_part, bl, sl, hl, p_pool, out);
  k_m1<<<256, 256, 0, stream>>>(p_pool, wm1, bm1, sm1, hm1, h1g);
  k_m2o<<<128, 256, 0, stream>>>(h1g, wm2, bm2, sm2, hm2, wout, bout, out);
}

// Round 5
// 355.518 us; speedup vs baseline: 1.0547x; 1.0215x over previous
//
#include <hip/hip_runtime.h>

#define DEV __device__ __forceinline__
DEV float relu_(float x) { return fmaxf(x, 0.0f); }

typedef __attribute__((ext_vector_type(4))) float f32x4;
typedef __attribute__((ext_vector_type(8))) __bf16 bf16x8;

DEV unsigned short bfbits(__bf16 b) { union { unsigned short s; __bf16 b; } x; x.b = b; return x.s; }
DEV __bf16 bffrom(unsigned short s) { union { unsigned short s; __bf16 b; } x; x.s = s; return x.b; }

// branchy top-5 insert (wave-coherent merge streams + scalar merge kernel)
DEV void knn_insert(float (&bd)[5], int (&bi)[5], float d, int j) {
  if (d >= bd[4]) return;
  bd[4] = d; bi[4] = j;
#pragma unroll
  for (int p = 4; p > 0; --p) {
    if (bd[p] < bd[p - 1]) {
      float td = bd[p]; bd[p] = bd[p - 1]; bd[p - 1] = td;
      int ti = bi[p]; bi[p] = bi[p - 1]; bi[p - 1] = ti;
    }
  }
}

// branchless EXACT top-5 insert (used in knn1 tree merge)
DEV void knn_insert_bl(float (&bd)[5], int (&bi)[5], float d, int j) {
#pragma unroll
  for (int p = 0; p < 5; ++p) {
    bool lt = d < bd[p];
    float nd = lt ? d : bd[p];
    float cd = lt ? bd[p] : d;
    int ni = lt ? j : bi[p];
    int ci = lt ? bi[p] : j;
    bd[p] = nd; d = cd;
    bi[p] = ni; j = ci;
  }
}

// sorted top-5 insert via med3: new[i] = med3(old[i-1], old[i], x); new[0]=min.
DEV void ins5(float (&b)[5], float x) {
  b[4] = __builtin_amdgcn_fmed3f(b[3], b[4], x);
  b[3] = __builtin_amdgcn_fmed3f(b[2], b[3], x);
  b[2] = __builtin_amdgcn_fmed3f(b[1], b[2], x);
  b[1] = __builtin_amdgcn_fmed3f(b[0], b[1], x);
  b[0] = fminf(b[0], x);
}

// branchless merge of two sorted ascending 5-lists -> 5 smallest of union, sorted.
// u_k = min over {b[k], max(a[i-1], b[k-i]) for i=1..k, a[k]}; symmetric in (a,b).
DEV void merge_net5(float (&a)[5], float b0, float b1, float b2, float b3, float b4) {
  float c0 = fminf(a[0], b0);
  float c1 = fminf(fminf(b1, a[1]), fmaxf(a[0], b0));
  float c2 = fminf(fminf(b2, a[2]), fminf(fmaxf(a[0], b1), fmaxf(a[1], b0)));
  float c3 = fminf(fminf(b3, a[3]),
                   fminf(fmaxf(a[0], b2), fminf(fmaxf(a[1], b1), fmaxf(a[2], b0))));
  float c4 = fminf(fminf(b4, a[4]),
                   fminf(fminf(fmaxf(a[0], b3), fmaxf(a[1], b2)),
                         fminf(fmaxf(a[2], b1), fmaxf(a[3], b0))));
  a[0] = c0; a[1] = c1; a[2] = c2; a[3] = c3; a[4] = c4;
}

// ---------------- Kernel FRONT: knn1 (blk<2048, SoA LDS) + uv (2048..3071) + preps ----------------
__global__ __launch_bounds__(256) void k_front(
    const float* __restrict__ pos, const float* __restrict__ w1a,
    const float* __restrict__ b1a, const float* __restrict__ w1b,
    const float* __restrict__ w1c, const float* __restrict__ w2,
    const float* __restrict__ wl,
    int* __restrict__ idx1, float* __restrict__ uR, float* __restrict__ vR,
    __bf16* __restrict__ wfh, __bf16* __restrict__ wfl,
    __bf16* __restrict__ wph, __bf16* __restrict__ wpl,
    __bf16* __restrict__ wlb) {
  __shared__ __align__(16) float smem[9472];
  int tid = threadIdx.x;
  int blk = blockIdx.x;
  if (blk < 2048) {
    float* xs = smem;             // SoA: xs[2048] ys[2048] zs[2048]
    float* sqs = smem + 6144;
    float* md = smem + 8192;
    int* mi = (int*)(smem + 8832);
    int b = blk >> 6, qc = blk & 63;
    const float* src = pos + b * 6144;
    for (int u = tid; u < 6144; u += 256) {
      float v = src[u];
      int p = u / 3, c = u - p * 3;
      smem[c * 2048 + p] = v;
    }
    __syncthreads();
    for (int u = tid; u < 2048; u += 256) {
      float x = xs[u], y = xs[2048 + u], z = xs[4096 + u];
      sqs[u] = fmaf(z, z, fmaf(y, y, x * x));
    }
    __syncthreads();
    int q = tid & 31, sub = tid >> 5;
    int qi = qc * 32 + q;
    float qx = xs[qi], qy = xs[2048 + qi], qz = xs[4096 + qi];
    float qsq = sqs[qi];
    // packed scan: idx (8 bits, j-j0) lives in low mantissa bits of d
    float bp[5] = {1e30f, 1e30f, 1e30f, 1e30f, 1e30f};
    int j0 = sub * 256;
    for (int j4 = 0; j4 < 64; ++j4) {
      int jb = j0 + j4 * 4;
      float4 xv = *(const float4*)(xs + jb);
      float4 yv = *(const float4*)(xs + 2048 + jb);
      float4 zv = *(const float4*)(xs + 4096 + jb);
      float4 sv = *(const float4*)(sqs + jb);
      float xa[4] = {xv.x, xv.y, xv.z, xv.w};
      float ya[4] = {yv.x, yv.y, yv.z, yv.w};
      float za[4] = {zv.x, zv.y, zv.z, zv.w};
      float sa[4] = {sv.x, sv.y, sv.z, sv.w};
#pragma unroll
      for (int c = 0; c < 4; ++c) {
        float dot = fmaf(qz, za[c], fmaf(qy, ya[c], qx * xa[c]));
        float d = fmaxf((qsq + sa[c]) - 2.0f * dot, 0.0f);
        unsigned u = (__float_as_uint(d) & 0xFFFFFF00u) | (unsigned)(j4 * 4 + c);
        ins5(bp, __uint_as_float(u));
      }
    }
    float bd[5]; int bi[5];
#pragma unroll
    for (int k = 0; k < 5; ++k) {
      unsigned u = __float_as_uint(bp[k]);
      bd[k] = __uint_as_float(u & 0xFFFFFF00u);
      bi[k] = j0 + (int)(u & 255u);
    }
    for (int half = 4; half >= 1; half >>= 1) {
      __syncthreads();
      if (sub >= half && sub < 2 * half) {
        int slot = (q * 4 + (sub - half)) * 5;
#pragma unroll
        for (int k = 0; k < 5; ++k) { md[slot + k] = bd[k]; mi[slot + k] = bi[k]; }
      }
      __syncthreads();
      if (sub < half) {
        int slot = (q * 4 + sub) * 5;
#pragma unroll
        for (int k = 0; k < 5; ++k) knn_insert_bl(bd, bi, md[slot + k], mi[slot + k]);
      }
    }
    if (sub == 0) {
      int* op = idx1 + (b * 2048 + qi) * 5;
#pragma unroll
      for (int k = 0; k < 5; ++k) op[k] = bi[k];
    }
  } else if (blk < 3072) {
    float* wAs = smem;
    float* bs = smem + 384;
    float* uS = smem + 448;
    float* vS = smem + 4800;
    for (int u = tid; u < 384; u += 256) wAs[u] = w1a[u];
    if (tid < 64) bs[tid] = b1a[tid];
    __syncthreads();
    int lane = tid & 63, fq = tid >> 6;
    int p0 = (blk - 2048) * 64;
    int p = p0 + lane;
    float x0 = pos[p * 3], x1 = pos[p * 3 + 1], x2 = pos[p * 3 + 2];
#pragma unroll
    for (int m = 0; m < 16; ++m) {
      int f = fq * 16 + m;
      float wt0 = wAs[f], wt1 = wAs[64 + f], wt2 = wAs[128 + f];
      float wb0 = wAs[192 + f], wb1 = wAs[256 + f], wb2 = wAs[320 + f];
      float uval = bs[f];
      uval = fmaf(x0, wt0 - wb0, uval);
      uval = fmaf(x1, wt1 - wb1, uval);
      uval = fmaf(x2, wt2 - wb2, uval);
      uS[lane * 68 + f] = uval;
      vS[lane * 68 + f] = fmaf(x2, wb2, fmaf(x1, wb1, x0 * wb0));
    }
    __syncthreads();
#pragma unroll
    for (int it = 0; it < 4; ++it) {
      int g = it * 1024 + tid * 4;
      int pl = g >> 6, f = g & 63;
      float4 uu = *(const float4*)(uS + pl * 68 + f);
      float4 vv = *(const float4*)(vS + pl * 68 + f);
      *(float4*)(uR + (size_t)p0 * 64 + g) = uu;
      *(float4*)(vR + (size_t)p0 * 64 + g) = vv;
    }
  } else {
    int pblk = blk - 3072;
    if (pblk < 4) {
      int t = pblk * 256 + tid;
      int m = t >> 9;
      int rem = t & 511;
      int nb = rem >> 7;
      int rem2 = rem & 127;
      int s = rem2 >> 6, lane = rem2 & 63;
      int k0 = s * 32 + (lane >> 4) * 8;
      int c = nb * 16 + (lane & 15);
      const float* W = m ? w1c : w1b;
      __bf16 oh[8], ol[8];
#pragma unroll
      for (int j = 0; j < 8; ++j) {
        float val = W[(k0 + j) * 64 + c];
        __bf16 h = (__bf16)val;
        oh[j] = h;
        ol[j] = (__bf16)(val - (float)h);
      }
      size_t off = (size_t)m * 4096 + ((size_t)((nb * 2 + s) * 64 + lane)) * 8;
      *(uint4*)(wfh + off) = *(const uint4*)oh;
      *(uint4*)(wfl + off) = *(const uint4*)ol;
    } else if (pblk < 12) {
      int t = (pblk - 4) * 256 + tid;
      int nb = t >> 7;
      int rem = t & 127;
      int ks = rem >> 6, lane = rem & 63;
      int k0 = ks * 32 + (lane >> 4) * 8;
      int col16 = lane & 15;
      __bf16 oh[8], ol[8];
#pragma unroll
      for (int j = 0; j < 8; ++j) {
        int k = k0 + j;
        float val;
        if (nb < 8) {
          int c = nb * 16 + col16;
          val = w2[k * 128 + c] - w2[(64 + k) * 128 + c];
        } else {
          int c = (nb - 8) * 16 + col16;
          val = w2[(64 + k) * 128 + c];
        }
        __bf16 h = (__bf16)val;
        oh[j] = h;
        ol[j] = (__bf16)(val - (float)h);
      }
      *(uint4*)(wph + (size_t)t * 8) = *(const uint4*)oh;
      *(uint4*)(wpl + (size_t)t * 8) = *(const uint4*)ol;
    } else {
      int t = (pblk - 12) * 256 + tid;
      int nt = t / 3072;
      int rem = t - nt * 3072;
      int ks = rem / 512;
      int rem2 = rem - ks * 512;
      int nb = rem2 >> 6, lane = rem2 & 63;
      int k0 = ks * 32 + (lane >> 4) * 8;
      int n = nt * 128 + nb * 16 + (lane & 15);
      __bf16 o[8];
#pragma unroll
      for (int j = 0; j < 8; ++j) o[j] = (__bf16)wl[(k0 + j) * 1024 + n];
      *(uint4*)(wlb + (size_t)t * 8) = *(const uint4*)o;
    }
  }
}

// ---------------- Kernel 2: EdgeConv1 layers 2/3 via hi/lo MFMA, barrier-free k-loop ----------------
__global__ __launch_bounds__(256) void k_edge1(
    const int* __restrict__ idx1, const float* __restrict__ uR,
    const float* __restrict__ vR,
    const float* __restrict__ s1a, const float* __restrict__ h1a,
    const float* __restrict__ b1b, const float* __restrict__ s1b,
    const float* __restrict__ h1b,
    const float* __restrict__ b1c, const float* __restrict__ s1c,
    const float* __restrict__ h1c,
    const __bf16* __restrict__ wfh, const __bf16* __restrict__ wfl,
    __bf16* __restrict__ xh, __bf16* __restrict__ xl,
    float* __restrict__ sqo, __bf16* __restrict__ xb) {
  __shared__ __align__(16) __bf16 Wh[8192], Wl[8192];
  __shared__ __align__(16) unsigned h2b[4 * 1088];
  int tid = threadIdx.x;
  int w = tid >> 6, lane = tid & 63;
  int quad = lane >> 4, lm = lane & 15;
#pragma unroll
  for (int it = 0; it < 4; ++it) {
    int u4 = it * 256 + tid;
    *(uint4*)(Wh + (size_t)u4 * 8) = *(const uint4*)(wfh + (size_t)u4 * 8);
    *(uint4*)(Wl + (size_t)u4 * 8) = *(const uint4*)(wfl + (size_t)u4 * 8);
  }
  int p0 = blockIdx.x * 64;
  int b = p0 >> 11;
  size_t bb = (size_t)b * 2048;
  int edge = p0 + w * 16 + lm;
  float sA[2][8], hA[2][8];
#pragma unroll
  for (int s = 0; s < 2; ++s)
#pragma unroll
    for (int j = 0; j < 8; ++j) {
      int k = s * 32 + quad * 8 + j;
      sA[s][j] = s1a[k]; hA[s][j] = h1a[k];
    }
  float bB[4], sB[4], hB[4], bC[4], sC[4], hC[4];
#pragma unroll
  for (int nb = 0; nb < 4; ++nb) {
    int c = nb * 16 + lm;
    bB[nb] = b1b[c]; sB[nb] = s1b[c]; hB[nb] = h1b[c];
    bC[nb] = b1c[c]; sC[nb] = s1c[c]; hC[nb] = h1c[c];
  }
  unsigned* h2w = h2b + w * 1088;
  f32x4 mmax[4];
#pragma unroll
  for (int nb = 0; nb < 4; ++nb)
    mmax[nb] = (f32x4){-3.4e38f, -3.4e38f, -3.4e38f, -3.4e38f};
  __syncthreads();
  const float* urow = uR + (size_t)edge * 64;
  for (int kk = 0; kk < 5; ++kk) {
    int jn = idx1[edge * 5 + kk];
    const float* vrow = vR + (bb + jn) * 64;
    bf16x8 Ah[2], Al[2];
#pragma unroll
    for (int s = 0; s < 2; ++s) {
      int off = s * 32 + quad * 8;
      float4 u0 = *(const float4*)(urow + off);
      float4 u1 = *(const float4*)(urow + off + 4);
      float4 v0 = *(const float4*)(vrow + off);
      float4 v1 = *(const float4*)(vrow + off + 4);
      float uv[8] = {u0.x + v0.x, u0.y + v0.y, u0.z + v0.z, u0.w + v0.w,
                     u1.x + v1.x, u1.y + v1.y, u1.z + v1.z, u1.w + v1.w};
      __bf16 th[8], tl[8];
#pragma unroll
      for (int j = 0; j < 8; ++j) {
        float val = relu_(uv[j]) * sA[s][j] + hA[s][j];
        __bf16 hb = (__bf16)val;
        th[j] = hb;
        tl[j] = (__bf16)(val - (float)hb);
      }
      Ah[s] = *(const bf16x8*)th;
      Al[s] = *(const bf16x8*)tl;
    }
#pragma unroll
    for (int nb = 0; nb < 4; ++nb) {
      bf16x8 Bh0 = *(const bf16x8*)(Wh + ((size_t)((nb * 2 + 0) * 64 + lane)) * 8);
      bf16x8 Bh1 = *(const bf16x8*)(Wh + ((size_t)((nb * 2 + 1) * 64 + lane)) * 8);
      bf16x8 Bl0 = *(const bf16x8*)(Wl + ((size_t)((nb * 2 + 0) * 64 + lane)) * 8);
      bf16x8 Bl1 = *(const bf16x8*)(Wl + ((size_t)((nb * 2 + 1) * 64 + lane)) * 8);
      f32x4 a2 = {0.f, 0.f, 0.f, 0.f};
      a2 = __builtin_amdgcn_mfma_f32_16x16x32_bf16(Ah[0], Bh0, a2, 0, 0, 0);
      a2 = __builtin_amdgcn_mfma_f32_16x16x32_bf16(Ah[1], Bh1, a2, 0, 0, 0);
      a2 = __builtin_amdgcn_mfma_f32_16x16x32_bf16(Ah[0], Bl0, a2, 0, 0, 0);
      a2 = __builtin_amdgcn_mfma_f32_16x16x32_bf16(Ah[1], Bl1, a2, 0, 0, 0);
      a2 = __builtin_amdgcn_mfma_f32_16x16x32_bf16(Al[0], Bh0, a2, 0, 0, 0);
      a2 = __builtin_amdgcn_mfma_f32_16x16x32_bf16(Al[1], Bh1, a2, 0, 0, 0);
#pragma unroll
      for (int r = 0; r < 4; ++r) {
        float vv2 = relu_(a2[r] + bB[nb]) * sB[nb] + hB[nb];
        __bf16 hb = (__bf16)vv2;
        __bf16 lb = (__bf16)(vv2 - (float)hb);
        h2w[(quad * 4 + r) * 68 + nb * 16 + lm] =
            (unsigned)bfbits(hb) | ((unsigned)bfbits(lb) << 16);
      }
    }
    bf16x8 A3h[2], A3l[2];
#pragma unroll
    for (int s = 0; s < 2; ++s) {
      const unsigned* rp = h2w + lm * 68 + s * 32 + quad * 8;
      uint4 da = *(const uint4*)rp;
      uint4 db = *(const uint4*)(rp + 4);
      unsigned dw[8] = {da.x, da.y, da.z, da.w, db.x, db.y, db.z, db.w};
      __bf16 th[8], tl[8];
#pragma unroll
      for (int j = 0; j < 8; ++j) {
        th[j] = bffrom((unsigned short)(dw[j] & 0xFFFFu));
        tl[j] = bffrom((unsigned short)(dw[j] >> 16));
      }
      A3h[s] = *(const bf16x8*)th;
      A3l[s] = *(const bf16x8*)tl;
    }
#pragma unroll
    for (int nb = 0; nb < 4; ++nb) {
      bf16x8 Bh0 = *(const bf16x8*)(Wh + 4096 + ((size_t)((nb * 2 + 0) * 64 + lane)) * 8);
      bf16x8 Bh1 = *(const bf16x8*)(Wh + 4096 + ((size_t)((nb * 2 + 1) * 64 + lane)) * 8);
      bf16x8 Bl0 = *(const bf16x8*)(Wl + 4096 + ((size_t)((nb * 2 + 0) * 64 + lane)) * 8);
      bf16x8 Bl1 = *(const bf16x8*)(Wl + 4096 + ((size_t)((nb * 2 + 1) * 64 + lane)) * 8);
      f32x4 a3 = {0.f, 0.f, 0.f, 0.f};
      a3 = __builtin_amdgcn_mfma_f32_16x16x32_bf16(A3h[0], Bh0, a3, 0, 0, 0);
      a3 = __builtin_amdgcn_mfma_f32_16x16x32_bf16(A3h[1], Bh1, a3, 0, 0, 0);
      a3 = __builtin_amdgcn_mfma_f32_16x16x32_bf16(A3h[0], Bl0, a3, 0, 0, 0);
      a3 = __builtin_amdgcn_mfma_f32_16x16x32_bf16(A3h[1], Bl1, a3, 0, 0, 0);
      a3 = __builtin_amdgcn_mfma_f32_16x16x32_bf16(A3l[0], Bh0, a3, 0, 0, 0);
      a3 = __builtin_amdgcn_mfma_f32_16x16x32_bf16(A3l[1], Bh1, a3, 0, 0, 0);
#pragma unroll
      for (int r = 0; r < 4; ++r) mmax[nb][r] = fmaxf(mmax[nb][r], a3[r]);
    }
  }
  float sqp[4] = {0.f, 0.f, 0.f, 0.f};
#pragma unroll
  for (int nb = 0; nb < 4; ++nb) {
    int c = nb * 16 + lm;
#pragma unroll
    for (int r = 0; r < 4; ++r) {
      float vv3 = relu_(mmax[nb][r] + bC[nb]) * sC[nb] + hC[nb];
      sqp[r] = fmaf(vv3, vv3, sqp[r]);
      __bf16 hb = (__bf16)vv3;
      __bf16 lb = (__bf16)(vv3 - (float)hb);
      int n = p0 + w * 16 + quad * 4 + r;
      xh[(size_t)n * 64 + c] = hb;
      xl[(size_t)n * 64 + c] = lb;
      xb[(size_t)n * 192 + c] = hb;
    }
  }
#pragma unroll
  for (int r = 0; r < 4; ++r) {
    float s = sqp[r];
    s += __shfl_xor(s, 1);
    s += __shfl_xor(s, 2);
    s += __shfl_xor(s, 4);
    s += __shfl_xor(s, 8);
    if (lm == 0) sqo[p0 + w * 16 + quad * 4 + r] = s;
  }
}

// ---------------- Kernel MID: knn2 half-scan (blk<2048) + pq_mfma (2048..3071) ----------------
// 256 thr, 26.6KB LDS (6 blocks/CU). knn2 split by candidate half across 2 blocks.
// T14 reg-prefetch staging; wave merge: 2 packed network stages (8-bit key) + 2 branchy.
__global__ __launch_bounds__(256) void k_mid(const __bf16* __restrict__ xh,
                                             const __bf16* __restrict__ xl,
                                             const float* __restrict__ sq,
                                             __bf16* __restrict__ scratch,
                                             const __bf16* __restrict__ wph,
                                             const __bf16* __restrict__ wpl,
                                             __bf16* __restrict__ Pb,
                                             __bf16* __restrict__ Qb) {
  __shared__ __align__(16) float smem[6656];
  int tid = threadIdx.x;
  int w = tid >> 6, lane = tid & 63;
  int quad = lane >> 4, lm = lane & 15;
  if (blockIdx.x < 2048) {
    __bf16* Bh = (__bf16*)smem;
    __bf16* Bl = (__bf16*)(smem + 2304);
    float* sqs = smem + 4608;
    int blk = blockIdx.x;
    int b = blk >> 6;
    int w6 = blk & 63;
    int qc = w6 >> 1, g = w6 & 1;
    int q0 = qc * 64;
    size_t bb = (size_t)b * 2048;
    for (int u = tid; u < 512; u += 256)
      *(float4*)(sqs + u * 4) = *(const float4*)(sq + bb + u * 4);
    const __bf16* qh = xh + (bb + q0 + w * 16 + lm) * 64 + quad * 8;
    const __bf16* ql = xl + (bb + q0 + w * 16 + lm) * 64 + quad * 8;
    bf16x8 Ah0 = *(const bf16x8*)(qh);
    bf16x8 Ah1 = *(const bf16x8*)(qh + 32);
    bf16x8 Al0 = *(const bf16x8*)(ql);
    bf16x8 Al1 = *(const bf16x8*)(ql + 32);
    // T14: staging pointers (row n, col cc) for both passes; tile stride 4096 elems
    int nu = tid >> 3, cu = tid & 7;
    const __bf16* ph0 = xh + (bb + (size_t)g * 1024 + nu) * 64 + cu * 8;
    const __bf16* pl0 = xl + (bb + (size_t)g * 1024 + nu) * 64 + cu * 8;
    __bf16* dh0 = Bh + nu * 72 + cu * 8;
    __bf16* dh1 = Bh + (nu + 32) * 72 + cu * 8;
    __bf16* dl0 = Bl + nu * 72 + cu * 8;
    __bf16* dl1 = Bl + (nu + 32) * 72 + cu * 8;
    uint4 rh0 = *(const uint4*)(ph0);
    uint4 rh1 = *(const uint4*)(ph0 + 2048);
    uint4 rl0 = *(const uint4*)(pl0);
    uint4 rl1 = *(const uint4*)(pl0 + 2048);
    __syncthreads();
    float qsq[4];
#pragma unroll
    for (int r = 0; r < 4; ++r) qsq[r] = sqs[q0 + w * 16 + quad * 4 + r];
    // packed scan: key6 = it*4+nt (6 bits) in low mantissa bits; lm + g implicit
    float bp[4][5];
#pragma unroll
    for (int r = 0; r < 4; ++r)
#pragma unroll
      for (int k = 0; k < 5; ++k) bp[r][k] = 1e30f;
    for (int it = 0; it < 16; ++it) {
      *(uint4*)dh0 = rh0;
      *(uint4*)dh1 = rh1;
      *(uint4*)dl0 = rl0;
      *(uint4*)dl1 = rl1;
      __syncthreads();
      if (it < 15) {  // prefetch next tile into regs; latency hides under scan
        const __bf16* p1 = ph0 + (it + 1) * 4096;
        const __bf16* p2 = pl0 + (it + 1) * 4096;
        rh0 = *(const uint4*)(p1);
        rh1 = *(const uint4*)(p1 + 2048);
        rl0 = *(const uint4*)(p2);
        rl1 = *(const uint4*)(p2 + 2048);
      }
      int ct = g * 16 + it;
#pragma unroll
      for (int nt = 0; nt < 4; ++nt) {
        const __bf16* bph = Bh + (nt * 16 + lm) * 72 + quad * 8;
        const __bf16* bpl = Bl + (nt * 16 + lm) * 72 + quad * 8;
        bf16x8 Bh0 = *(const bf16x8*)(bph);
        bf16x8 Bh1 = *(const bf16x8*)(bph + 32);
        bf16x8 Bl0 = *(const bf16x8*)(bpl);
        bf16x8 Bl1 = *(const bf16x8*)(bpl + 32);
        f32x4 acc = {0.f, 0.f, 0.f, 0.f};
        acc = __builtin_amdgcn_mfma_f32_16x16x32_bf16(Ah0, Bh0, acc, 0, 0, 0);
        acc = __builtin_amdgcn_mfma_f32_16x16x32_bf16(Ah1, Bh1, acc, 0, 0, 0);
        acc = __builtin_amdgcn_mfma_f32_16x16x32_bf16(Ah0, Bl0, acc, 0, 0, 0);
        acc = __builtin_amdgcn_mfma_f32_16x16x32_bf16(Ah1, Bl1, acc, 0, 0, 0);
        acc = __builtin_amdgcn_mfma_f32_16x16x32_bf16(Al0, Bh0, acc, 0, 0, 0);
        acc = __builtin_amdgcn_mfma_f32_16x16x32_bf16(Al1, Bh1, acc, 0, 0, 0);
        float csq = sqs[ct * 64 + nt * 16 + lm];
        unsigned key = (unsigned)(it * 4 + nt);
#pragma unroll
        for (int r = 0; r < 4; ++r) {
          float d = fmaxf((qsq[r] + csq) - 2.0f * acc[r], 0.0f);
          unsigned u = (__float_as_uint(d) & 0xFFFFFFC0u) | key;
          ins5(bp[r], __uint_as_float(u));
        }
      }
      __syncthreads();
    }
    // repack 6->8 bit keys (+2 bits of lm): truncation 2^-15 (knn1-proven level)
#pragma unroll
    for (int r = 0; r < 4; ++r)
#pragma unroll
      for (int k = 0; k < 5; ++k) {
        unsigned u = __float_as_uint(bp[r][k]);
        bp[r][k] = __uint_as_float((u & 0xFFFFFF00u) | ((u & 63u) << 2) |
                                   (unsigned)(lm & 3));
      }
    // stages m=1,2: branchless packed merge network
#pragma unroll
    for (int m = 1; m <= 2; m <<= 1) {
#pragma unroll
      for (int r = 0; r < 4; ++r) {
        float b0 = __shfl_xor(bp[r][0], m);
        float b1 = __shfl_xor(bp[r][1], m);
        float b2 = __shfl_xor(bp[r][2], m);
        float b3 = __shfl_xor(bp[r][3], m);
        float b4 = __shfl_xor(bp[r][4], m);
        merge_net5(bp[r], b0, b1, b2, b3, b4);
      }
    }
    // unpack: cid = g*1024 + key6*16 + (lmbase | lm2)
    int lmb = lm & ~3;
    float bd[4][5];
    int bi[4][5];
#pragma unroll
    for (int r = 0; r < 4; ++r)
#pragma unroll
      for (int k = 0; k < 5; ++k) {
        unsigned u = __float_as_uint(bp[r][k]);
        bd[r][k] = __uint_as_float(u & 0xFFFFFF00u);
        unsigned k8 = u & 255u;
        bi[r][k] = (g << 10) | (((int)(k8 >> 2)) << 4) | (lmb | (int)(k8 & 3));
      }
    // stages m=4,8: exact branchy merge with explicit indices
#pragma unroll
    for (int m = 4; m <= 8; m <<= 1) {
#pragma unroll
      for (int r = 0; r < 4; ++r) {
        float od[5]; int oi[5];
#pragma unroll
        for (int k = 0; k < 5; ++k) {
          od[k] = __shfl_xor(bd[r][k], m);
          oi[k] = __shfl_xor(bi[r][k], m);
        }
#pragma unroll
        for (int k = 0; k < 5; ++k) knn_insert(bd[r], bi[r], od[k], oi[k]);
      }
    }
    if (lm == 0) {
#pragma unroll
      for (int r = 0; r < 4; ++r) {
        int qi = q0 + w * 16 + quad * 4 + r;
        uint2* sp = (uint2*)((char*)scratch + (size_t)(bb + qi) * 384 + 128 + g * 40);
#pragma unroll
        for (int k = 0; k < 5; ++k) {
          uint2 v;
          v.x = __float_as_uint(bd[r][k]);
          v.y = (unsigned)bi[r][k];
          sp[k] = v;
        }
      }
    }
  } else {
    __bf16* Wh = (__bf16*)smem;
    __bf16* Wl = (__bf16*)(smem + 2048);
    int n0 = (blockIdx.x - 2048) * 64;
    const __bf16* ah = xh + (size_t)(n0 + w * 16 + lm) * 64 + quad * 8;
    const __bf16* al = xl + (size_t)(n0 + w * 16 + lm) * 64 + quad * 8;
    bf16x8 Ah0 = *(const bf16x8*)(ah);
    bf16x8 Ah1 = *(const bf16x8*)(ah + 32);
    bf16x8 Al0 = *(const bf16x8*)(al);
    bf16x8 Al1 = *(const bf16x8*)(al + 32);
    for (int chunk = 0; chunk < 4; ++chunk) {
      __syncthreads();
#pragma unroll
      for (int it = 0; it < 2; ++it) {
        int unit = it * 256 + tid;
        *(uint4*)(Wh + (size_t)unit * 8) =
            *(const uint4*)(wph + (size_t)chunk * 4096 + (size_t)unit * 8);
        *(uint4*)(Wl + (size_t)unit * 8) =
            *(const uint4*)(wpl + (size_t)chunk * 4096 + (size_t)unit * 8);
      }
      __syncthreads();
#pragma unroll
      for (int nb4 = 0; nb4 < 4; ++nb4) {
        int nb = chunk * 4 + nb4;
        bf16x8 Bh0 = *(const bf16x8*)(Wh + ((size_t)(nb4 * 2 + 0) * 64 + lane) * 8);
        bf16x8 Bh1 = *(const bf16x8*)(Wh + ((size_t)(nb4 * 2 + 1) * 64 + lane) * 8);
        bf16x8 Bl0 = *(const bf16x8*)(Wl + ((size_t)(nb4 * 2 + 0) * 64 + lane) * 8);
        bf16x8 Bl1 = *(const bf16x8*)(Wl + ((size_t)(nb4 * 2 + 1) * 64 + lane) * 8);
        f32x4 acc = {0.f, 0.f, 0.f, 0.f};
        acc = __builtin_amdgcn_mfma_f32_16x16x32_bf16(Ah0, Bh0, acc, 0, 0, 0);
        acc = __builtin_amdgcn_mfma_f32_16x16x32_bf16(Ah1, Bh1, acc, 0, 0, 0);
        acc = __builtin_amdgcn_mfma_f32_16x16x32_bf16(Ah0, Bl0, acc, 0, 0, 0);
        acc = __builtin_amdgcn_mfma_f32_16x16x32_bf16(Ah1, Bl1, acc, 0, 0, 0);
        acc = __builtin_amdgcn_mfma_f32_16x16x32_bf16(Al0, Bh0, acc, 0, 0, 0);
        acc = __builtin_amdgcn_mfma_f32_16x16x32_bf16(Al1, Bh1, acc, 0, 0, 0);
        bool isP = (nb < 8);
        __bf16* base = isP ? Pb : Qb;
        int col = (isP ? nb : nb - 8) * 16 + lm;
#pragma unroll
        for (int r = 0; r < 4; ++r) {
          int n = n0 + w * 16 + quad * 4 + r;
          base[(size_t)n * 128 + col] = (__bf16)acc[r];
        }
      }
    }
  }
}

// ---------------- Kernel MERGE: combine the two candidate-half top-5 partials -> idx2 ----------------
__global__ __launch_bounds__(256) void k_kmerge(const __bf16* __restrict__ scratch,
                                                int* __restrict__ idx2) {
  int n = blockIdx.x * 256 + threadIdx.x;
  const uint2* sp = (const uint2*)((const char*)scratch + (size_t)n * 384 + 128);
  float bd[5]; int bi[5];
#pragma unroll
  for (int k = 0; k < 5; ++k) {
    uint2 v = sp[k];
    bd[k] = __uint_as_float(v.x);
    bi[k] = (int)v.y;
  }
#pragma unroll
  for (int k = 0; k < 5; ++k) {
    uint2 v = sp[5 + k];
    knn_insert(bd, bi, __uint_as_float(v.x), (int)v.y);
  }
  int* op = idx2 + (size_t)n * 5;
#pragma unroll
  for (int k = 0; k < 5; ++k) op[k] = bi[k];
}

// ---------------- Kernel 4b: gather-max + activation, 4 channels/lane ----------------
__global__ __launch_bounds__(256) void k_gmax(const __bf16* __restrict__ Pb,
                                              const __bf16* __restrict__ Qb,
                                              const int* __restrict__ idx2,
                                              const float* __restrict__ b2,
                                              const float* __restrict__ s2,
                                              const float* __restrict__ h2v,
                                              __bf16* __restrict__ xb) {
  int tid = threadIdx.x;
  int c4 = tid & 31, p = tid >> 5;  // 32 lanes/point, 8 points/block
  int n = blockIdx.x * 8 + p;
  int b = n >> 11;
  const int* ip = idx2 + n * 5;
  int c0 = c4 * 4;
  float m[4] = {-3.4e38f, -3.4e38f, -3.4e38f, -3.4e38f};
#pragma unroll
  for (int k = 0; k < 5; ++k) {
    int j = ip[k];
    uint2 q = *(const uint2*)(Qb + ((size_t)(b * 2048 + j)) * 128 + c0);
    m[0] = fmaxf(m[0], (float)bffrom((unsigned short)(q.x & 0xFFFFu)));
    m[1] = fmaxf(m[1], (float)bffrom((unsigned short)(q.x >> 16)));
    m[2] = fmaxf(m[2], (float)bffrom((unsigned short)(q.y & 0xFFFFu)));
    m[3] = fmaxf(m[3], (float)bffrom((unsigned short)(q.y >> 16)));
  }
  uint2 pv = *(const uint2*)(Pb + (size_t)n * 128 + c0);
  float pvf[4] = {(float)bffrom((unsigned short)(pv.x & 0xFFFFu)),
                  (float)bffrom((unsigned short)(pv.x >> 16)),
                  (float)bffrom((unsigned short)(pv.y & 0xFFFFu)),
                  (float)bffrom((unsigned short)(pv.y >> 16))};
  __bf16 o[4];
#pragma unroll
  for (int i = 0; i < 4; ++i) {
    float v = pvf[i] + m[i] + b2[c0 + i];
    o[i] = (__bf16)(relu_(v) * s2[c0 + i] + h2v[c0 + i]);
  }
  uint2 ov;
  ov.x = (unsigned)bfbits(o[0]) | ((unsigned)bfbits(o[1]) << 16);
  ov.y = (unsigned)bfbits(o[2]) | ((unsigned)bfbits(o[3]) << 16);
  *(uint2*)(xb + (size_t)n * 192 + 64 + c0) = ov;
}

// ---------------- Kernel 5: bf16 MFMA GEMM fused point-max, A staged once, ng loop ----------------
__global__ __launch_bounds__(256) void k_linl_mfma(const __bf16* __restrict__ xb,
                                                   const __bf16* __restrict__ wlb,
                                                   float* __restrict__ pool_part) {
  __shared__ __align__(16) __bf16 Aall[12288];  // [mb4][ks6][lane64][8]
  __shared__ __align__(16) __bf16 Bl[8192];     // [nt2][nb8][lane64][8]
  int tid = threadIdx.x;
  int w = tid >> 6, lane = tid & 63;
  int mg = blockIdx.x;
  int n0 = mg << 6;
  int quad = lane >> 4, lm = lane & 15;
#pragma unroll
  for (int it = 0; it < 6; ++it) {
    int unit = it * 256 + tid;           // 0..1535
    int mb = unit / 384;
    int rem = unit - mb * 384;
    int ks = rem >> 6, ln = rem & 63;
    int lmm = ln & 15, qd = ln >> 4;
    const uint4* ga = (const uint4*)(xb + (size_t)(n0 + mb * 16 + lmm) * 192 + ks * 32 + qd * 8);
    *(uint4*)(Aall + ((size_t)(mb * 6 + ks) * 64 + ln) * 8) = *ga;
  }
  for (int ng = 0; ng < 4; ++ng) {
    f32x4 acc[4][4];
#pragma unroll
    for (int i = 0; i < 4; ++i)
#pragma unroll
      for (int j = 0; j < 4; ++j) acc[i][j] = (f32x4){0.f, 0.f, 0.f, 0.f};
    for (int ks = 0; ks < 6; ++ks) {
      __syncthreads();  // protect prev B reads (and covers initial A staging)
#pragma unroll
      for (int nt2 = 0; nt2 < 2; ++nt2) {
#pragma unroll
        for (int u = 0; u < 2; ++u) {
          int unit = u * 256 + tid;
          const uint4* gb = (const uint4*)(wlb + ((size_t)((ng * 2 + nt2) * 6 + ks)) * 4096 + (size_t)unit * 8);
          *(uint4*)(Bl + (size_t)nt2 * 4096 + (size_t)unit * 8) = *gb;
        }
      }
      __syncthreads();
      bf16x8 af[4], bfr[4];
#pragma unroll
      for (int i = 0; i < 4; ++i)
        af[i] = *(const bf16x8*)(Aall + ((size_t)(i * 6 + ks) * 64 + lane) * 8);
      int nt2 = w >> 1, nbb = (w & 1) * 4;
#pragma unroll
      for (int j = 0; j < 4; ++j)
        bfr[j] = *(const bf16x8*)(Bl + (size_t)nt2 * 4096 + ((size_t)((nbb + j) * 64 + lane)) * 8);
#pragma unroll
      for (int i = 0; i < 4; ++i)
#pragma unroll
        for (int j = 0; j < 4; ++j)
          acc[i][j] = __builtin_amdgcn_mfma_f32_16x16x32_bf16(af[i], bfr[j], acc[i][j], 0, 0, 0);
    }
#pragma unroll
    for (int j = 0; j < 4; ++j) {
      float m = -3.4e38f;
#pragma unroll
      for (int i = 0; i < 4; ++i)
#pragma unroll
        for (int r = 0; r < 4; ++r) m = fmaxf(m, acc[i][j][r]);
      m = fmaxf(m, __shfl_xor(m, 16));
      m = fmaxf(m, __shfl_xor(m, 32));
      if (quad == 0) {
        int ch = ng * 256 + (w >> 1) * 128 + (w & 1) * 64 + j * 16 + lm;
        pool_part[(size_t)mg * 1024 + ch] = m;
      }
    }
  }
}

// ---------------- Kernel 6a: pool merge (32-way max) + lin/bn -> p[32][1024]; zeroes out ----------------
__global__ __launch_bounds__(256) void k_pool(const float* __restrict__ pool_part,
                                              const float* __restrict__ bl,
                                              const float* __restrict__ sl,
                                              const float* __restrict__ hl,
                                              float* __restrict__ p,
                                              float* __restrict__ out) {
  int b = blockIdx.x >> 2, cb = blockIdx.x & 3;
  int c = cb * 256 + threadIdx.x;
  const float* src = pool_part + (size_t)(b * 32) * 1024 + c;
  float m0 = -3.4e38f, m1 = -3.4e38f, m2 = -3.4e38f, m3 = -3.4e38f;
#pragma unroll
  for (int t = 0; t < 32; t += 4) {
    m0 = fmaxf(m0, src[(size_t)t * 1024]);
    m1 = fmaxf(m1, src[(size_t)(t + 1) * 1024]);
    m2 = fmaxf(m2, src[(size_t)(t + 2) * 1024]);
    m3 = fmaxf(m3, src[(size_t)(t + 3) * 1024]);
  }
  float m = fmaxf(fmaxf(m0, m1), fmaxf(m2, m3));
  p[b * 1024 + c] = relu_(m + bl[c]) * sl[c] + hl[c];
  if (blockIdx.x == 0 && threadIdx.x < 64) out[threadIdx.x] = 0.0f;
}

// ---------------- Kernel 6b: h1 = act(p @ wm1) ----------------
__global__ __launch_bounds__(256) void k_m1(const float* __restrict__ p,
                                            const float* __restrict__ wm1,
                                            const float* __restrict__ bm1,
                                            const float* __restrict__ sm1,
                                            const float* __restrict__ hm1,
                                            float* __restrict__ h1) {
  __shared__ float p_s[1024];
  __shared__ float red[4][64];
  int b = blockIdx.x >> 3, cb = blockIdx.x & 7;
  int tid = threadIdx.x;
  for (int u = tid; u < 1024; u += 256) p_s[u] = p[b * 1024 + u];
  __syncthreads();
  int c64 = tid & 63, q = tid >> 6;
  int C = cb * 64 + c64;
  int f0 = q * 256;
  const float* W = wm1 + (size_t)f0 * 512 + C;
  float a[8] = {0.f, 0.f, 0.f, 0.f, 0.f, 0.f, 0.f, 0.f};
  for (int f = 0; f < 256; f += 8) {
#pragma unroll
    for (int u = 0; u < 8; ++u)
      a[u] = fmaf(p_s[f0 + f + u], W[(size_t)(f + u) * 512], a[u]);
  }
  red[q][c64] = ((a[0] + a[1]) + (a[2] + a[3])) + ((a[4] + a[5]) + (a[6] + a[7]));
  __syncthreads();
  if (tid < 64) {
    float t = (red[0][tid] + red[1][tid]) + (red[2][tid] + red[3][tid]);
    int C2 = cb * 64 + tid;
    h1[b * 512 + C2] = relu_(t + bm1[C2]) * sm1[C2] + hm1[C2];
  }
}

// ---------------- Kernel 6c: h2 = act(h1 @ wm2); out += h2-slice @ wout (atomic partials) ----------------
__global__ __launch_bounds__(256) void k_m2o(const float* __restrict__ h1,
                                             const float* __restrict__ wm2,
                                             const float* __restrict__ bm2,
                                             const float* __restrict__ sm2,
                                             const float* __restrict__ hm2,
                                             const float* __restrict__ wout,
                                             const float* __restrict__ bout,
                                             float* __restrict__ out) {
  __shared__ float h1_s[512];
  __shared__ float red[4][64];
  int b = blockIdx.x >> 2, cb = blockIdx.x & 3;
  int tid = threadIdx.x;
  for (int u = tid; u < 512; u += 256) h1_s[u] = h1[b * 512 + u];
  __syncthreads();
  int c64 = tid & 63, q = tid >> 6;
  int C = cb * 64 + c64;
  int f0 = q * 128;
  const float* W = wm2 + (size_t)f0 * 256 + C;
  float a[4] = {0.f, 0.f, 0.f, 0.f};
  for (int f = 0; f < 128; f += 4) {
#pragma unroll
    for (int u = 0; u < 4; ++u)
      a[u] = fmaf(h1_s[f0 + f + u], W[(size_t)(f + u) * 256], a[u]);
  }
  red[q][c64] = (a[0] + a[1]) + (a[2] + a[3]);
  __syncthreads();
  if (tid < 64) {
    float t = (red[0][tid] + red[1][tid]) + (red[2][tid] + red[3][tid]);
    int C2 = cb * 64 + tid;
    float h2v = relu_(t + bm2[C2]) * sm2[C2] + hm2[C2];
    float2 wv = *(const float2*)(wout + C2 * 2);
    float v0 = h2v * wv.x, v1 = h2v * wv.y;
#pragma unroll
    for (int m = 1; m < 64; m <<= 1) {
      v0 += __shfl_xor(v0, m);
      v1 += __shfl_xor(v1, m);
    }
    if (tid == 0) {
      if (cb == 0) { v0 += bout[0]; v1 += bout[1]; }
      atomicAdd(&out[b * 2], v0);
      atomicAdd(&out[b * 2 + 1], v1);
    }
  }
}

extern "C" void kernel_launch(void* const* d_in, const int* in_sizes, int n_in,
                              void* d_out, int out_size, void* d_ws, size_t ws_size,
                              hipStream_t stream) {
  const float* pos = (const float*)d_in[0];
  const float* w1a = (const float*)d_in[1];
  const float* b1a = (const float*)d_in[2];
  const float* s1a = (const float*)d_in[3];
  const float* h1a = (const float*)d_in[4];
  const float* w1b = (const float*)d_in[5];
  const float* b1b = (const float*)d_in[6];
  const float* s1b = (const float*)d_in[7];
  const float* h1b = (const float*)d_in[8];
  const float* w1c = (const float*)d_in[9];
  const float* b1c = (const float*)d_in[10];
  const float* s1c = (const float*)d_in[11];
  const float* h1c = (const float*)d_in[12];
  const float* w2 = (const float*)d_in[13];
  const float* b2 = (const float*)d_in[14];
  const float* s2 = (const float*)d_in[15];
  const float* h2 = (const float*)d_in[16];
  const float* wl = (const float*)d_in[17];
  const float* bl = (const float*)d_in[18];
  const float* sl = (const float*)d_in[19];
  const float* hl = (const float*)d_in[20];
  const float* wm1 = (const float*)d_in[21];
  const float* bm1 = (const float*)d_in[22];
  const float* sm1 = (const float*)d_in[23];
  const float* hm1 = (const float*)d_in[24];
  const float* wm2 = (const float*)d_in[25];
  const float* bm2 = (const float*)d_in[26];
  const float* sm2 = (const float*)d_in[27];
  const float* hm2 = (const float*)d_in[28];
  const float* wout = (const float*)d_in[29];
  const float* bout = (const float*)d_in[30];
  float* out = (float*)d_out;

  // workspace: xh | xl | Pb | Qb | xb | idx | sq | wph/wpl/wfh/wfl | wlb (~77.6 MB)
  float* base = (float*)d_ws;
  __bf16* xh = (__bf16*)base;
  __bf16* xl = (__bf16*)(base + 2097152);
  float* PbF = base + 4194304;
  float* QbF = PbF + 4194304;
  float* xbF = QbF + 4194304;
  int* idx = (int*)(xbF + 6291456);
  float* sq = (float*)(idx + 327680);
  __bf16* wph = (__bf16*)(sq + 65536);
  __bf16* wpl = (__bf16*)(sq + 65536 + 8192);
  __bf16* wfh = (__bf16*)(sq + 65536 + 16384);
  __bf16* wfl = (__bf16*)(sq + 65536 + 20480);
  __bf16* wlb = (__bf16*)(sq + 65536 + 24576);
  __bf16* Pb = (__bf16*)PbF;
  __bf16* Qb = (__bf16*)QbF;
  __bf16* xb = (__bf16*)xbF;
  float* uR = PbF;                                // alias (dead until k_mid's pq)
  float* vR = QbF;
  float* pool_part = base + 131072;               // in xh region: dead by linl
  float* p_pool = base + 1179648;                 // 32x1024 f32, after pool_part (xh region)
  float* h1g = base + 1212416;                    // 32x512 f32 (xh region)

  k_front<<<3180, 256, 0, stream>>>(pos, w1a, b1a, w1b, w1c, w2, wl, idx, uR, vR,
                                    wfh, wfl, wph, wpl, wlb);
  k_edge1<<<1024, 256, 0, stream>>>(idx, uR, vR, s1a, h1a, b1b, s1b, h1b, b1c,
                                    s1c, h1c, wfh, wfl, xh, xl, sq, xb);
  k_mid<<<3072, 256, 0, stream>>>(xh, xl, sq, xb, wph, wpl, Pb, Qb);
  k_kmerge<<<256, 256, 0, stream>>>(xb, idx);
  k_gmax<<<8192, 256, 0, stream>>>(Pb, Qb, idx, b2, s2, h2, xb);
  k_linl_mfma<<<1024, 256, 0, stream>>>(xb, wlb, pool_part);
  k_pool<<<128, 256, 0, stream>>>(pool_part, bl, sl, hl, p_pool, out);
  k_m1<<<256, 256, 0, stream>>>(p_pool, wm1, bm1, sm1, hm1, h1g);
  k_m2o<<<128, 256, 0, stream>>>(h1g, wm2, bm2, sm2, hm2, wout, bout, out);
}